// Round 2
// baseline (3366.403 us; speedup 1.0000x reference)
//
#include <hip/hip_runtime.h>
#include <hip/hip_bf16.h>

// Dims
#define BATCH 16
#define SEQ 1024
#define NROWS (BATCH*SEQ)          // 16384 tokens
#define IN_DIM 768
#define DM 128
#define DIP 644
#define DI 256
#define CDIM 384
#define DST 64
#define NH 4
#define HD 64

// ---------------- fc1 + positional embedding ----------------
// x (16384,768) f32 @ W (768,128) f32 + b + PE[t] -> h f32
__global__ void fc1_kernel(const float* __restrict__ x, const float* __restrict__ W,
                           const float* __restrict__ bias, float* __restrict__ h) {
    __shared__ float xs[8][IN_DIM];
    int tid = threadIdx.x;              // 128
    int row0 = blockIdx.x * 8;
    for (int r = 0; r < 8; r++) {
        const float* xr = x + (size_t)(row0 + r) * IN_DIM;
        for (int c = tid; c < IN_DIM; c += 128) xs[r][c] = xr[c];
    }
    __syncthreads();
    float acc[8] = {0.f,0.f,0.f,0.f,0.f,0.f,0.f,0.f};
    for (int k = 0; k < IN_DIM; k++) {
        float w = W[(size_t)k * DM + tid];
        #pragma unroll
        for (int r = 0; r < 8; r++) acc[r] += xs[r][k] * w;
    }
    float bv = bias[tid];
    // positional embedding: col c, i2 = c&~1, div = exp(-i2*ln(1e4)/128)
    float div = expf(-(float)(tid & ~1) * 0.071955784f);  // ln(10000)/128
    for (int r = 0; r < 8; r++) {
        int row = row0 + r;
        int t = row & (SEQ - 1);
        float arg = (float)t * div;
        float pe = (tid & 1) ? cosf(arg) : sinf(arg);
        h[(size_t)row * DM + tid] = acc[r] + bv + pe;
    }
}

// ---------------- LayerNorm over 128 ----------------
__global__ void ln_kernel(const float* __restrict__ h, const float* __restrict__ lnw,
                          const float* __restrict__ lnb, float* __restrict__ hn, int layer) {
    int row = blockIdx.x; int tid = threadIdx.x; // 64 threads
    float v0 = h[(size_t)row * DM + tid];
    float v1 = h[(size_t)row * DM + 64 + tid];
    float s = v0 + v1;
    #pragma unroll
    for (int o = 32; o; o >>= 1) s += __shfl_xor(s, o);
    float mu = s * (1.f / 128.f);
    float d0 = v0 - mu, d1 = v1 - mu;
    float q = d0 * d0 + d1 * d1;
    #pragma unroll
    for (int o = 32; o; o >>= 1) q += __shfl_xor(q, o);
    float rstd = rsqrtf(q * (1.f / 128.f) + 1e-5f);
    hn[(size_t)row * DM + tid]      = d0 * rstd * lnw[layer*DM + tid]      + lnb[layer*DM + tid];
    hn[(size_t)row * DM + 64 + tid] = d1 * rstd * lnw[layer*DM + 64 + tid] + lnb[layer*DM + 64 + tid];
}

// ---------------- in_proj: hn (16384,128) @ W(128,644) -> zx ----------------
__global__ void inproj_kernel(const float* __restrict__ hn, const float* __restrict__ W,
                              float* __restrict__ zx, int layer) {
    __shared__ float xs[8][DM];
    const float* Wl = W + (size_t)layer * DM * DIP;
    int tid = threadIdx.x;               // 256
    int row0 = blockIdx.x * 8;
    for (int idx = tid; idx < 8 * DM; idx += 256)
        xs[idx >> 7][idx & 127] = hn[(size_t)(row0 + (idx >> 7)) * DM + (idx & 127)];
    __syncthreads();
    float a0[8] = {0}, a1[8] = {0}, a2[8] = {0};
    int c0 = tid, c1 = tid + 256, c2 = tid + 512;
    bool v2 = (c2 < DIP);
    for (int k = 0; k < DM; k++) {
        float w0 = Wl[(size_t)k * DIP + c0];
        float w1 = Wl[(size_t)k * DIP + c1];
        float w2 = v2 ? Wl[(size_t)k * DIP + c2] : 0.f;
        #pragma unroll
        for (int r = 0; r < 8; r++) {
            float xv = xs[r][k];
            a0[r] += xv * w0; a1[r] += xv * w1; a2[r] += xv * w2;
        }
    }
    for (int r = 0; r < 8; r++) {
        size_t base = (size_t)(row0 + r) * DIP;
        zx[base + c0] = a0[r];
        zx[base + c1] = a1[r];
        if (v2) zx[base + c2] = a2[r];
    }
}

// ---------------- causal conv(4) + SiLU, plus dt/dA ----------------
__global__ void conv_kernel(const float* __restrict__ zx, const float* __restrict__ convw,
                            const float* __restrict__ convb, const float* __restrict__ dt_bias,
                            const float* __restrict__ A_log, float* __restrict__ xc,
                            float* __restrict__ dtb, float* __restrict__ dAb, int layer) {
    int row = blockIdx.x;  // token
    int c = threadIdx.x;   // 384
    int l = row & (SEQ - 1);
    const float* cw = convw + (size_t)layer * 4 * CDIM;
    float acc = convb[layer * CDIM + c];
    #pragma unroll
    for (int k = 0; k < 4; k++) {
        int dl = l + k - 3;
        if (dl >= 0) acc += cw[k * CDIM + c] * zx[(size_t)(row + k - 3) * DIP + DI + c];
    }
    float sv = acc / (1.f + expf(-acc));
    xc[(size_t)row * CDIM + c] = sv;
    if (c < NH) {
        float raw = zx[(size_t)row * DIP + DI + CDIM + c] + dt_bias[layer * NH + c];
        float dt = (raw > 20.f) ? raw : log1pf(expf(raw));
        float A = -expf(A_log[layer * NH + c]);
        dtb[row * NH + c] = dt;
        dAb[row * NH + c] = expf(dt * A);
    }
}

// ---------------- sequential SSM scan: one wave per (b,h) ----------------
__global__ void scan_kernel(const float* __restrict__ xc, const float* __restrict__ dtb,
                            const float* __restrict__ dAb, const float* __restrict__ Dp,
                            float* __restrict__ y, int layer) {
    int bh = blockIdx.x;           // 64 blocks
    int b = bh >> 2, hh = bh & 3;
    int p = threadIdx.x;           // 64
    float Dph = Dp[layer * NH + hh];
    float st[DST];
    #pragma unroll
    for (int n = 0; n < DST; n++) st[n] = 0.f;
    int rowbase = b * SEQ;
    for (int t = 0; t < SEQ; t++) {
        int row = rowbase + t;
        const float* xr = xc + (size_t)row * CDIM;
        float xv  = xr[hh * HD + p];
        float dtv = dtb[row * NH + hh];
        float dAv = dAb[row * NH + hh];
        float dtx = dtv * xv;
        const float* Bp2 = xr + DI;        // uniform address
        const float* Cp2 = xr + DI + DST;  // uniform address
        float yp = 0.f;
        #pragma unroll
        for (int n = 0; n < DST; n++) {
            float Bn = Bp2[n];
            float Cn = Cp2[n];
            st[n] = dAv * st[n] + dtx * Bn;
            yp += st[n] * Cn;
        }
        y[(size_t)row * DI + hh * HD + p] = yp + Dph * xv;
    }
}

// ---------------- gate (silu(z)) + RMSNorm over 256 ----------------
__global__ void gaterms_kernel(const float* __restrict__ zx, const float* __restrict__ rmsw,
                               float* __restrict__ y, int layer) {
    int row = blockIdx.x; int c = threadIdx.x; // 256
    float z = zx[(size_t)row * DIP + c];
    float g = z / (1.f + expf(-z));
    float v = y[(size_t)row * DI + c] * g;
    float q = v * v;
    #pragma unroll
    for (int o = 32; o; o >>= 1) q += __shfl_xor(q, o);
    __shared__ float sred[4];
    if ((c & 63) == 0) sred[c >> 6] = q;
    __syncthreads();
    float tot = sred[0] + sred[1] + sred[2] + sred[3];
    float rstd = rsqrtf(tot * (1.f / 256.f) + 1e-5f);
    y[(size_t)row * DI + c] = v * rstd * rmsw[layer * DI + c];
}

// ---------------- out_proj (256->128) + residual into h ----------------
__global__ void outproj_kernel(const float* __restrict__ y, const float* __restrict__ W,
                               float* __restrict__ h, int layer) {
    __shared__ float ys[8][DI];
    const float* Wl = W + (size_t)layer * DI * DM;
    int tid = threadIdx.x;      // 128
    int row0 = blockIdx.x * 8;
    for (int idx = tid; idx < 8 * DI; idx += 128)
        ys[idx >> 8][idx & 255] = y[(size_t)(row0 + (idx >> 8)) * DI + (idx & 255)];
    __syncthreads();
    float acc[8] = {0};
    for (int k = 0; k < DI; k++) {
        float w = Wl[(size_t)k * DM + tid];
        #pragma unroll
        for (int r = 0; r < 8; r++) acc[r] += ys[r][k] * w;
    }
    for (int r = 0; r < 8; r++) {
        size_t i = (size_t)(row0 + r) * DM + tid;
        h[i] = h[i] + acc[r];
    }
}

// ---------------- fc2a: h(128) @ W1(128,128) + b1, leaky_relu(0.1) ----------------
__global__ void fc2a_kernel(const float* __restrict__ h, const float* __restrict__ W,
                            const float* __restrict__ bias, float* __restrict__ h2) {
    __shared__ float xs[8][DM];
    int tid = threadIdx.x;      // 128
    int row0 = blockIdx.x * 8;
    for (int idx = tid; idx < 8 * DM; idx += 128)
        xs[idx >> 7][idx & 127] = h[(size_t)(row0 + (idx >> 7)) * DM + (idx & 127)];
    __syncthreads();
    float acc[8] = {0};
    for (int k = 0; k < DM; k++) {
        float w = W[(size_t)k * DM + tid];
        #pragma unroll
        for (int r = 0; r < 8; r++) acc[r] += xs[r][k] * w;
    }
    float bv = bias[tid];
    for (int r = 0; r < 8; r++) {
        float o = acc[r] + bv;
        h2[(size_t)(row0 + r) * DM + tid] = (o > 0.f) ? o : 0.1f * o;
    }
}

// ---------------- fc2b: h2(128) @ W2(128,6) + b2 -> out f32 ----------------
__global__ void fc2b_kernel(const float* __restrict__ h2, const float* __restrict__ W,
                            const float* __restrict__ bias, float* __restrict__ out) {
    int idx = blockIdx.x * 256 + threadIdx.x;   // 98304 total
    int row = idx / 6, c = idx % 6;
    float acc = bias[c];
    const float* hr = h2 + (size_t)row * DM;
    #pragma unroll 16
    for (int k = 0; k < DM; k++) acc += hr[k] * W[k * 6 + c];
    out[idx] = acc;
}

extern "C" void kernel_launch(void* const* d_in, const int* in_sizes, int n_in,
                              void* d_out, int out_size, void* d_ws, size_t ws_size,
                              hipStream_t stream) {
    const float* x       = (const float*)d_in[0];
    const float* fc1_W   = (const float*)d_in[1];
    const float* fc1_b   = (const float*)d_in[2];
    const float* ln_w    = (const float*)d_in[3];
    const float* ln_b    = (const float*)d_in[4];
    const float* in_W    = (const float*)d_in[5];
    const float* conv_w  = (const float*)d_in[6];
    const float* conv_b  = (const float*)d_in[7];
    const float* dt_bias = (const float*)d_in[8];
    const float* A_log   = (const float*)d_in[9];
    const float* Dp      = (const float*)d_in[10];
    const float* rms_w   = (const float*)d_in[11];
    const float* out_W   = (const float*)d_in[12];
    const float* fc2_W1  = (const float*)d_in[13];
    const float* fc2_b1  = (const float*)d_in[14];
    const float* fc2_W2  = (const float*)d_in[15];
    const float* fc2_b2  = (const float*)d_in[16];
    float* out = (float*)d_out;

    float* ws = (float*)d_ws;
    float* h   = ws;                       // 16384*128
    float* hn  = h   + (size_t)NROWS * DM;
    float* zx  = hn  + (size_t)NROWS * DM; // 16384*644
    float* xc  = zx  + (size_t)NROWS * DIP;// 16384*384
    float* dtb = xc  + (size_t)NROWS * CDIM;
    float* dAb = dtb + (size_t)NROWS * NH;
    float* yb  = dAb + (size_t)NROWS * NH; // 16384*256
    float* h2  = yb  + (size_t)NROWS * DI; // 16384*128

    fc1_kernel<<<NROWS / 8, 128, 0, stream>>>(x, fc1_W, fc1_b, h);

    for (int layer = 0; layer < 2; layer++) {
        ln_kernel<<<NROWS, 64, 0, stream>>>(h, ln_w, ln_b, hn, layer);
        inproj_kernel<<<NROWS / 8, 256, 0, stream>>>(hn, in_W, zx, layer);
        conv_kernel<<<NROWS, CDIM, 0, stream>>>(zx, conv_w, conv_b, dt_bias, A_log,
                                                xc, dtb, dAb, layer);
        scan_kernel<<<BATCH * NH, 64, 0, stream>>>(xc, dtb, dAb, Dp, yb, layer);
        gaterms_kernel<<<NROWS, 256, 0, stream>>>(zx, rms_w, yb, layer);
        outproj_kernel<<<NROWS / 8, 128, 0, stream>>>(yb, out_W, h, layer);
    }

    fc2a_kernel<<<NROWS / 8, 128, 0, stream>>>(h, fc2_W1, fc2_b1, h2);
    fc2b_kernel<<<NROWS * 6 / 256, 256, 0, stream>>>(h2, fc2_W2, fc2_b2, out);
}

// Round 3
// 744.780 us; speedup vs baseline: 4.5200x; 4.5200x over previous
//
#include <hip/hip_runtime.h>
#include <hip/hip_bf16.h>

// Dims
#define BATCH 16
#define SEQ 1024
#define NROWS (BATCH*SEQ)          // 16384 tokens
#define IN_DIM 768
#define DM 128
#define DIP 644
#define DI 256
#define CDIM 384
#define DST 64
#define NH 4
#define HD 64
#define CHUNK 64
#define NCHUNK (SEQ/CHUNK)         // 16

// ---------------- fc1 + positional embedding ----------------
__global__ void fc1_kernel(const float* __restrict__ x, const float* __restrict__ W,
                           const float* __restrict__ bias, float* __restrict__ h) {
    __shared__ float xs[8][IN_DIM];
    int tid = threadIdx.x;              // 128
    int row0 = blockIdx.x * 8;
    for (int r = 0; r < 8; r++) {
        const float* xr = x + (size_t)(row0 + r) * IN_DIM;
        for (int c = tid; c < IN_DIM; c += 128) xs[r][c] = xr[c];
    }
    __syncthreads();
    float acc[8] = {0.f,0.f,0.f,0.f,0.f,0.f,0.f,0.f};
    for (int k = 0; k < IN_DIM; k++) {
        float w = W[(size_t)k * DM + tid];
        #pragma unroll
        for (int r = 0; r < 8; r++) acc[r] += xs[r][k] * w;
    }
    float bv = bias[tid];
    float div = expf(-(float)(tid & ~1) * 0.071955784f);  // ln(10000)/128
    for (int r = 0; r < 8; r++) {
        int row = row0 + r;
        int t = row & (SEQ - 1);
        float arg = (float)t * div;
        float pe = (tid & 1) ? cosf(arg) : sinf(arg);
        h[(size_t)row * DM + tid] = acc[r] + bv + pe;
    }
}

// ---------------- LayerNorm over 128 ----------------
__global__ void ln_kernel(const float* __restrict__ h, const float* __restrict__ lnw,
                          const float* __restrict__ lnb, float* __restrict__ hn, int layer) {
    int row = blockIdx.x; int tid = threadIdx.x; // 64 threads
    float v0 = h[(size_t)row * DM + tid];
    float v1 = h[(size_t)row * DM + 64 + tid];
    float s = v0 + v1;
    #pragma unroll
    for (int o = 32; o; o >>= 1) s += __shfl_xor(s, o);
    float mu = s * (1.f / 128.f);
    float d0 = v0 - mu, d1 = v1 - mu;
    float q = d0 * d0 + d1 * d1;
    #pragma unroll
    for (int o = 32; o; o >>= 1) q += __shfl_xor(q, o);
    float rstd = rsqrtf(q * (1.f / 128.f) + 1e-5f);
    hn[(size_t)row * DM + tid]      = d0 * rstd * lnw[layer*DM + tid]      + lnb[layer*DM + tid];
    hn[(size_t)row * DM + 64 + tid] = d1 * rstd * lnw[layer*DM + 64 + tid] + lnb[layer*DM + 64 + tid];
}

// ---------------- in_proj: hn (16384,128) @ W(128,644) -> zx ----------------
__global__ void inproj_kernel(const float* __restrict__ hn, const float* __restrict__ W,
                              float* __restrict__ zx, int layer) {
    __shared__ float xs[8][DM];
    const float* Wl = W + (size_t)layer * DM * DIP;
    int tid = threadIdx.x;               // 256
    int row0 = blockIdx.x * 8;
    for (int idx = tid; idx < 8 * DM; idx += 256)
        xs[idx >> 7][idx & 127] = hn[(size_t)(row0 + (idx >> 7)) * DM + (idx & 127)];
    __syncthreads();
    float a0[8] = {0}, a1[8] = {0}, a2[8] = {0};
    int c0 = tid, c1 = tid + 256, c2 = tid + 512;
    bool v2 = (c2 < DIP);
    for (int k = 0; k < DM; k++) {
        float w0 = Wl[(size_t)k * DIP + c0];
        float w1 = Wl[(size_t)k * DIP + c1];
        float w2 = v2 ? Wl[(size_t)k * DIP + c2] : 0.f;
        #pragma unroll
        for (int r = 0; r < 8; r++) {
            float xv = xs[r][k];
            a0[r] += xv * w0; a1[r] += xv * w1; a2[r] += xv * w2;
        }
    }
    for (int r = 0; r < 8; r++) {
        size_t base = (size_t)(row0 + r) * DIP;
        zx[base + c0] = a0[r];
        zx[base + c1] = a1[r];
        if (v2) zx[base + c2] = a2[r];
    }
}

// ---------------- causal conv(4) + SiLU, plus dt ----------------
__global__ void conv_kernel(const float* __restrict__ zx, const float* __restrict__ convw,
                            const float* __restrict__ convb, const float* __restrict__ dt_bias,
                            float* __restrict__ xc, float* __restrict__ dtb, int layer) {
    int row = blockIdx.x;  // token
    int c = threadIdx.x;   // 384
    int l = row & (SEQ - 1);
    const float* cw = convw + (size_t)layer * 4 * CDIM;
    float acc = convb[layer * CDIM + c];
    #pragma unroll
    for (int k = 0; k < 4; k++) {
        int dl = l + k - 3;
        if (dl >= 0) acc += cw[k * CDIM + c] * zx[(size_t)(row + k - 3) * DIP + DI + c];
    }
    float sv = acc / (1.f + expf(-acc));
    xc[(size_t)row * CDIM + c] = sv;
    if (c < NH) {
        float raw = zx[(size_t)row * DIP + DI + CDIM + c] + dt_bias[layer * NH + c];
        float dt = (raw > 20.f) ? raw : log1pf(expf(raw));
        dtb[row * NH + c] = dt;
    }
}

// ---------------- chunk A: per-chunk local end-state + decay ----------------
// grid: BATCH*NH*NCHUNK (b-major: blockIdx = (b*NH+h)*NCHUNK + c), block 256
__global__ void chunk_state_kernel(const float* __restrict__ xc, const float* __restrict__ dtb,
                                   const float* __restrict__ A_log, float* __restrict__ Sloc,
                                   float* __restrict__ decay, int layer) {
    __shared__ float xh_s[CHUNK][HD];    // 16 KB
    __shared__ float B_s[CHUNK][DST];    // 16 KB
    __shared__ float wst[CHUNK];
    int bid = blockIdx.x;
    int c  = bid & (NCHUNK - 1);
    int hh = (bid >> 4) & (NH - 1);
    int b  = bid >> 6;
    int tid = threadIdx.x;
    int row0 = b * SEQ + c * CHUNK;
    float A = -expf(A_log[layer * NH + hh]);

    for (int idx = tid; idx < CHUNK * 64; idx += 256) {
        int t = idx >> 6, col = idx & 63;
        const float* xr = xc + (size_t)(row0 + t) * CDIM;
        xh_s[t][col] = xr[hh * HD + col];
        B_s[t][col]  = xr[DI + col];
    }
    if (tid < CHUNK) {
        float dtv = dtb[(row0 + tid) * NH + hh];
        float l = dtv * A;
        #pragma unroll
        for (int o = 1; o < 64; o <<= 1) { float v = __shfl_up(l, o); if (tid >= o) l += v; }
        float Ltot = __shfl(l, 63);
        wst[tid] = expf(Ltot - l) * dtv;
        if (tid == 63) decay[bid] = expf(Ltot);
    }
    __syncthreads();

    int p = tid & 63;
    int n0 = (tid >> 6) * 16;
    float s[16];
    #pragma unroll
    for (int j = 0; j < 16; j++) s[j] = 0.f;
    for (int t = 0; t < CHUNK; t++) {
        float xv = xh_s[t][p] * wst[t];
        #pragma unroll
        for (int j = 0; j < 16; j++) s[j] += xv * B_s[t][n0 + j];
    }
    float* Sp = Sloc + (size_t)bid * (HD * DST);
    #pragma unroll
    for (int j = 0; j < 16; j++) Sp[(n0 + j) * 64 + p] = s[j];  // layout [n][p]
}

// ---------------- chunk B: inter-chunk recurrence (16 steps) ----------------
// grid: BATCH*NH, block 256; each thread owns 16 flat state elements
__global__ void chunk_scan_kernel(const float* __restrict__ Sloc, const float* __restrict__ decay,
                                  float* __restrict__ hstart) {
    int bh = blockIdx.x;
    int tid = threadIdx.x;
    float hreg[16];
    #pragma unroll
    for (int k = 0; k < 16; k++) hreg[k] = 0.f;
    for (int c = 0; c < NCHUNK; c++) {
        size_t base = ((size_t)bh * NCHUNK + c) * (HD * DST);
        float d = decay[bh * NCHUNK + c];
        #pragma unroll
        for (int k = 0; k < 16; k++) {
            int i = tid + k * 256;
            hstart[base + i] = hreg[k];
            hreg[k] = d * hreg[k] + Sloc[base + i];
        }
    }
}

// ---------------- chunk C: outputs ----------------
// y_t[p] = sum_{s<=t} exp(L[t]-L[s]) dt_s (C_t.B_s) x_s[p] + exp(L[t]) C_t.hstart[:,p] + Dp x_t[p]
__global__ void chunk_out_kernel(const float* __restrict__ xc, const float* __restrict__ dtb,
                                 const float* __restrict__ A_log, const float* __restrict__ Dpw,
                                 const float* __restrict__ hstart, float* __restrict__ y, int layer) {
    __shared__ float xh_s[CHUNK][HD];    // 16 KB
    __shared__ float BG[CHUNK][DST + 1]; // 16.25 KB: B in phase1/2, G in phase3
    __shared__ float C_s[CHUNK][DST];    // 16 KB
    __shared__ float hst[DST][HD];       // 16 KB, [n][p]
    __shared__ float Ls[CHUNK], dts[CHUNK];
    int bid = blockIdx.x;
    int c  = bid & (NCHUNK - 1);
    int hh = (bid >> 4) & (NH - 1);
    int b  = bid >> 6;
    int tid = threadIdx.x;
    int row0 = b * SEQ + c * CHUNK;
    float A = -expf(A_log[layer * NH + hh]);
    float Dph = Dpw[layer * NH + hh];

    for (int idx = tid; idx < CHUNK * 64; idx += 256) {
        int t = idx >> 6, col = idx & 63;
        const float* xr = xc + (size_t)(row0 + t) * CDIM;
        xh_s[t][col] = xr[hh * HD + col];
        BG[t][col]   = xr[DI + col];
        C_s[t][col]  = xr[DI + DST + col];
    }
    {
        const float* hs = hstart + (size_t)bid * (HD * DST);
        for (int idx = tid; idx < HD * DST; idx += 256)
            ((float*)hst)[idx] = hs[idx];   // same flat [n][p] layout
    }
    if (tid < CHUNK) {
        float dtv = dtb[(row0 + tid) * NH + hh];
        float l = dtv * A;
        #pragma unroll
        for (int o = 1; o < 64; o <<= 1) { float v = __shfl_up(l, o); if (tid >= o) l += v; }
        Ls[tid] = l;
        dts[tid] = dtv;
    }
    __syncthreads();

    // phase 2: Gram matrix with decay, into registers
    float g[16];
    #pragma unroll
    for (int k = 0; k < 16; k++) {
        int i = tid + k * 256;
        int t = i >> 6, s = i & 63;
        float m = 0.f;
        if (s <= t) {
            #pragma unroll 16
            for (int n = 0; n < DST; n++) m += C_s[t][n] * BG[s][n];
            m *= expf(Ls[t] - Ls[s]) * dts[s];
        }
        g[k] = m;
    }
    __syncthreads();
    #pragma unroll
    for (int k = 0; k < 16; k++) {
        int i = tid + k * 256;
        int t = i >> 6, s = i & 63;
        BG[t][s] = g[k];
    }
    __syncthreads();

    // phase 3: outputs. 16 t's per thread, all lanes in a wave share t.
    int p = tid & 63;
    int tg = tid >> 6;
    for (int j = 0; j < 16; j++) {
        int t = tg * 16 + j;
        float acc = Dph * xh_s[t][p];
        float sv = 0.f;
        #pragma unroll 16
        for (int n = 0; n < DST; n++) sv += C_s[t][n] * hst[n][p];
        acc += expf(Ls[t]) * sv;
        float iv = 0.f;
        #pragma unroll 16
        for (int s = 0; s < CHUNK; s++) iv += BG[t][s] * xh_s[s][p];
        acc += iv;
        y[(size_t)(row0 + t) * DI + hh * HD + p] = acc;
    }
}

// ---------------- gate (silu(z)) + RMSNorm over 256 ----------------
__global__ void gaterms_kernel(const float* __restrict__ zx, const float* __restrict__ rmsw,
                               float* __restrict__ y, int layer) {
    int row = blockIdx.x; int c = threadIdx.x; // 256
    float z = zx[(size_t)row * DIP + c];
    float g = z / (1.f + expf(-z));
    float v = y[(size_t)row * DI + c] * g;
    float q = v * v;
    #pragma unroll
    for (int o = 32; o; o >>= 1) q += __shfl_xor(q, o);
    __shared__ float sred[4];
    if ((c & 63) == 0) sred[c >> 6] = q;
    __syncthreads();
    float tot = sred[0] + sred[1] + sred[2] + sred[3];
    float rstd = rsqrtf(tot * (1.f / 256.f) + 1e-5f);
    y[(size_t)row * DI + c] = v * rstd * rmsw[layer * DI + c];
}

// ---------------- out_proj (256->128) + residual into h ----------------
__global__ void outproj_kernel(const float* __restrict__ y, const float* __restrict__ W,
                               float* __restrict__ h, int layer) {
    __shared__ float ys[8][DI];
    const float* Wl = W + (size_t)layer * DI * DM;
    int tid = threadIdx.x;      // 128
    int row0 = blockIdx.x * 8;
    for (int idx = tid; idx < 8 * DI; idx += 128)
        ys[idx >> 8][idx & 255] = y[(size_t)(row0 + (idx >> 8)) * DI + (idx & 255)];
    __syncthreads();
    float acc[8] = {0};
    for (int k = 0; k < DI; k++) {
        float w = Wl[(size_t)k * DM + tid];
        #pragma unroll
        for (int r = 0; r < 8; r++) acc[r] += ys[r][k] * w;
    }
    for (int r = 0; r < 8; r++) {
        size_t i = (size_t)(row0 + r) * DM + tid;
        h[i] = h[i] + acc[r];
    }
}

// ---------------- fc2a ----------------
__global__ void fc2a_kernel(const float* __restrict__ h, const float* __restrict__ W,
                            const float* __restrict__ bias, float* __restrict__ h2) {
    __shared__ float xs[8][DM];
    int tid = threadIdx.x;      // 128
    int row0 = blockIdx.x * 8;
    for (int idx = tid; idx < 8 * DM; idx += 128)
        xs[idx >> 7][idx & 127] = h[(size_t)(row0 + (idx >> 7)) * DM + (idx & 127)];
    __syncthreads();
    float acc[8] = {0};
    for (int k = 0; k < DM; k++) {
        float w = W[(size_t)k * DM + tid];
        #pragma unroll
        for (int r = 0; r < 8; r++) acc[r] += xs[r][k] * w;
    }
    float bv = bias[tid];
    for (int r = 0; r < 8; r++) {
        float o = acc[r] + bv;
        h2[(size_t)(row0 + r) * DM + tid] = (o > 0.f) ? o : 0.1f * o;
    }
}

// ---------------- fc2b ----------------
__global__ void fc2b_kernel(const float* __restrict__ h2, const float* __restrict__ W,
                            const float* __restrict__ bias, float* __restrict__ out) {
    int idx = blockIdx.x * 256 + threadIdx.x;   // 98304 total
    int row = idx / 6, c = idx % 6;
    float acc = bias[c];
    const float* hr = h2 + (size_t)row * DM;
    #pragma unroll 16
    for (int k = 0; k < DM; k++) acc += hr[k] * W[k * 6 + c];
    out[idx] = acc;
}

extern "C" void kernel_launch(void* const* d_in, const int* in_sizes, int n_in,
                              void* d_out, int out_size, void* d_ws, size_t ws_size,
                              hipStream_t stream) {
    const float* x       = (const float*)d_in[0];
    const float* fc1_W   = (const float*)d_in[1];
    const float* fc1_b   = (const float*)d_in[2];
    const float* ln_w    = (const float*)d_in[3];
    const float* ln_b    = (const float*)d_in[4];
    const float* in_W    = (const float*)d_in[5];
    const float* conv_w  = (const float*)d_in[6];
    const float* conv_b  = (const float*)d_in[7];
    const float* dt_bias = (const float*)d_in[8];
    const float* A_log   = (const float*)d_in[9];
    const float* Dp      = (const float*)d_in[10];
    const float* rms_w   = (const float*)d_in[11];
    const float* out_W   = (const float*)d_in[12];
    const float* fc2_W1  = (const float*)d_in[13];
    const float* fc2_b1  = (const float*)d_in[14];
    const float* fc2_W2  = (const float*)d_in[15];
    const float* fc2_b2  = (const float*)d_in[16];
    float* out = (float*)d_out;

    float* ws = (float*)d_ws;
    float* h     = ws;                          // 16384*128
    float* hn    = h     + (size_t)NROWS * DM;
    float* zx    = hn    + (size_t)NROWS * DM;  // 16384*644
    float* xc    = zx    + (size_t)NROWS * DIP; // 16384*384
    float* dtb   = xc    + (size_t)NROWS * CDIM;// 16384*4
    float* yb    = dtb   + (size_t)NROWS * NH;  // 16384*256
    float* h2    = yb    + (size_t)NROWS * DI;  // 16384*128
    float* Sloc  = h2    + (size_t)NROWS * DM;  // 1024*4096
    float* hstr  = Sloc  + (size_t)BATCH*NH*NCHUNK*HD*DST;
    float* decay = hstr  + (size_t)BATCH*NH*NCHUNK*HD*DST; // 1024

    fc1_kernel<<<NROWS / 8, 128, 0, stream>>>(x, fc1_W, fc1_b, h);

    for (int layer = 0; layer < 2; layer++) {
        ln_kernel<<<NROWS, 64, 0, stream>>>(h, ln_w, ln_b, hn, layer);
        inproj_kernel<<<NROWS / 8, 256, 0, stream>>>(hn, in_W, zx, layer);
        conv_kernel<<<NROWS, CDIM, 0, stream>>>(zx, conv_w, conv_b, dt_bias, xc, dtb, layer);
        chunk_state_kernel<<<BATCH*NH*NCHUNK, 256, 0, stream>>>(xc, dtb, A_log, Sloc, decay, layer);
        chunk_scan_kernel<<<BATCH*NH, 256, 0, stream>>>(Sloc, decay, hstr);
        chunk_out_kernel<<<BATCH*NH*NCHUNK, 256, 0, stream>>>(xc, dtb, A_log, Dp, hstr, yb, layer);
        gaterms_kernel<<<NROWS, 256, 0, stream>>>(zx, rms_w, yb, layer);
        outproj_kernel<<<NROWS / 8, 128, 0, stream>>>(yb, out_W, h, layer);
    }

    fc2a_kernel<<<NROWS / 8, 128, 0, stream>>>(h, fc2_W1, fc2_b1, h2);
    fc2b_kernel<<<NROWS * 6 / 256, 256, 0, stream>>>(h2, fc2_W2, fc2_b2, out);
}

// Round 4
// 630.931 us; speedup vs baseline: 5.3356x; 1.1804x over previous
//
#include <hip/hip_runtime.h>
#include <hip/hip_bf16.h>

// Dims
#define BATCH 16
#define SEQ 1024
#define NROWS (BATCH*SEQ)          // 16384 tokens
#define IN_DIM 768
#define DM 128
#define DIP 644
#define DI 256
#define CDIM 384
#define DST 64
#define NH 4
#define HD 64
#define CHUNK 64
#define NCHUNK (SEQ/CHUNK)         // 16

typedef __attribute__((ext_vector_type(8))) short short8;
typedef __attribute__((ext_vector_type(4))) float float4v;

// f32 -> bf16 (RNE) as raw short
__device__ __forceinline__ short f2b(float f) {
    unsigned u = __builtin_bit_cast(unsigned, f);
    u += 0x7fffu + ((u >> 16) & 1u);
    return (short)(u >> 16);
}

// ============================================================
// Generic MFMA GEMM pattern: block = 512 thr (8 waves), tile M=64 x N=128,
// K staged 64 at a time in LDS. A: act f32 (row-major, ld=LDA), B: W f32
// (row-major, ld=LDB). Wave w: rows (w&3)*16..+15, n-tiles (w>>2)*4..+3.
// LDS: As[64][72] shorts, Bt[128][72] shorts (B transposed).
// ============================================================
#define GEMM_PROLOGUE() \
    int tid = threadIdx.x; \
    int lane = tid & 63; \
    int m = lane & 15; \
    int kq = (lane >> 4) * 8; \
    int w = tid >> 6; \
    int mrow = (w & 3) * 16; \
    int ngrp = w >> 2; \
    int a_off = (mrow + m) * 72 + kq; \
    int b_off = (ngrp * 64 + m) * 72 + kq; \
    float4v acc[4]; \
    acc[0] = (float4v)0.f; acc[1] = (float4v)0.f; acc[2] = (float4v)0.f; acc[3] = (float4v)0.f;

#define GEMM_STAGE_A(srcptr, LDA, row0, k0) \
    for (int idx = tid; idx < 64 * 64; idx += 512) { \
        int r = idx >> 6, k = idx & 63; \
        As[r * 72 + k] = f2b(srcptr[(size_t)((row0) + r) * (LDA) + (k0) + k]); \
    }

#define GEMM_COMPUTE_TILE() \
    { \
        short8 a0 = *reinterpret_cast<const short8*>(&As[a_off]); \
        short8 a1 = *reinterpret_cast<const short8*>(&As[a_off + 32]); \
        _Pragma("unroll") \
        for (int nt = 0; nt < 4; nt++) { \
            short8 b0 = *reinterpret_cast<const short8*>(&Bt[b_off + nt * 16 * 72]); \
            short8 b1 = *reinterpret_cast<const short8*>(&Bt[b_off + nt * 16 * 72 + 32]); \
            acc[nt] = __builtin_amdgcn_mfma_f32_16x16x32_bf16(a0, b0, acc[nt], 0, 0, 0); \
            acc[nt] = __builtin_amdgcn_mfma_f32_16x16x32_bf16(a1, b1, acc[nt], 0, 0, 0); \
        } \
    }

// ---------------- fc1 (MFMA): x(16384,768)@W(768,128)+b+PE -> h ----------------
__global__ __launch_bounds__(512) void fc1_mfma(const float* __restrict__ x,
                                                const float* __restrict__ W,
                                                const float* __restrict__ bias,
                                                float* __restrict__ h) {
    __shared__ short As[64 * 72];
    __shared__ short Bt[128 * 72];
    GEMM_PROLOGUE();
    int row0 = blockIdx.x * 64;
    for (int kt = 0; kt < 12; kt++) {
        int k0 = kt * 64;
        if (kt) __syncthreads();
        GEMM_STAGE_A(x, IN_DIM, row0, k0);
        for (int idx = tid; idx < 64 * 128; idx += 512) {
            int kk = idx >> 7, n = idx & 127;
            Bt[n * 72 + kk] = f2b(W[(size_t)(k0 + kk) * DM + n]);
        }
        __syncthreads();
        GEMM_COMPUTE_TILE();
    }
    #pragma unroll
    for (int nt = 0; nt < 4; nt++) {
        int col = ngrp * 64 + nt * 16 + m;
        float bv = bias[col];
        float div = expf(-(float)(col & ~1) * 0.071955784f);
        #pragma unroll
        for (int r = 0; r < 4; r++) {
            int row = row0 + mrow + (lane >> 4) * 4 + r;
            int t = row & (SEQ - 1);
            float arg = (float)t * div;
            float pe = (col & 1) ? cosf(arg) : sinf(arg);
            h[(size_t)row * DM + col] = acc[nt][r] + bv + pe;
        }
    }
}

// ---------------- in_proj (MFMA): hn@W(128,644) -> zx ----------------
__global__ __launch_bounds__(512) void inproj_mfma(const float* __restrict__ hn,
                                                   const float* __restrict__ W,
                                                   float* __restrict__ zx, int layer) {
    __shared__ short As[64 * 72];
    __shared__ short Bt[128 * 72];
    GEMM_PROLOGUE();
    int row0 = blockIdx.x * 64;
    int ncol0 = blockIdx.y * 128;
    const float* Wl = W + (size_t)layer * DM * DIP;
    for (int kt = 0; kt < 2; kt++) {
        int k0 = kt * 64;
        if (kt) __syncthreads();
        GEMM_STAGE_A(hn, DM, row0, k0);
        for (int idx = tid; idx < 64 * 128; idx += 512) {
            int kk = idx >> 7, n = idx & 127;
            int col = ncol0 + n;
            Bt[n * 72 + kk] = (col < DIP) ? f2b(Wl[(size_t)(k0 + kk) * DIP + col]) : (short)0;
        }
        __syncthreads();
        GEMM_COMPUTE_TILE();
    }
    #pragma unroll
    for (int nt = 0; nt < 4; nt++) {
        int col = ncol0 + ngrp * 64 + nt * 16 + m;
        if (col < DIP) {
            #pragma unroll
            for (int r = 0; r < 4; r++) {
                int row = row0 + mrow + (lane >> 4) * 4 + r;
                zx[(size_t)row * DIP + col] = acc[nt][r];
            }
        }
    }
}

// ---------------- out_proj (MFMA): yb(256)@W(256,128) + residual -> h ----------------
__global__ __launch_bounds__(512) void outproj_mfma(const float* __restrict__ y,
                                                    const float* __restrict__ W,
                                                    float* __restrict__ h, int layer) {
    __shared__ short As[64 * 72];
    __shared__ short Bt[128 * 72];
    GEMM_PROLOGUE();
    int row0 = blockIdx.x * 64;
    const float* Wl = W + (size_t)layer * DI * DM;
    for (int kt = 0; kt < 4; kt++) {
        int k0 = kt * 64;
        if (kt) __syncthreads();
        GEMM_STAGE_A(y, DI, row0, k0);
        for (int idx = tid; idx < 64 * 128; idx += 512) {
            int kk = idx >> 7, n = idx & 127;
            Bt[n * 72 + kk] = f2b(Wl[(size_t)(k0 + kk) * DM + n]);
        }
        __syncthreads();
        GEMM_COMPUTE_TILE();
    }
    #pragma unroll
    for (int nt = 0; nt < 4; nt++) {
        int col = ngrp * 64 + nt * 16 + m;
        #pragma unroll
        for (int r = 0; r < 4; r++) {
            int row = row0 + mrow + (lane >> 4) * 4 + r;
            size_t i = (size_t)row * DM + col;
            h[i] = h[i] + acc[nt][r];
        }
    }
}

// ---------------- fc2a (MFMA): h@W1(128,128)+b1, leaky 0.1 -> h2 ----------------
__global__ __launch_bounds__(512) void fc2a_mfma(const float* __restrict__ h,
                                                 const float* __restrict__ W,
                                                 const float* __restrict__ bias,
                                                 float* __restrict__ h2) {
    __shared__ short As[64 * 72];
    __shared__ short Bt[128 * 72];
    GEMM_PROLOGUE();
    int row0 = blockIdx.x * 64;
    for (int kt = 0; kt < 2; kt++) {
        int k0 = kt * 64;
        if (kt) __syncthreads();
        GEMM_STAGE_A(h, DM, row0, k0);
        for (int idx = tid; idx < 64 * 128; idx += 512) {
            int kk = idx >> 7, n = idx & 127;
            Bt[n * 72 + kk] = f2b(W[(size_t)(k0 + kk) * DM + n]);
        }
        __syncthreads();
        GEMM_COMPUTE_TILE();
    }
    #pragma unroll
    for (int nt = 0; nt < 4; nt++) {
        int col = ngrp * 64 + nt * 16 + m;
        float bv = bias[col];
        #pragma unroll
        for (int r = 0; r < 4; r++) {
            int row = row0 + mrow + (lane >> 4) * 4 + r;
            float o = acc[nt][r] + bv;
            h2[(size_t)row * DM + col] = (o > 0.f) ? o : 0.1f * o;
        }
    }
}

// ---------------- LayerNorm over 128 ----------------
__global__ void ln_kernel(const float* __restrict__ h, const float* __restrict__ lnw,
                          const float* __restrict__ lnb, float* __restrict__ hn, int layer) {
    int row = blockIdx.x; int tid = threadIdx.x; // 64 threads
    float v0 = h[(size_t)row * DM + tid];
    float v1 = h[(size_t)row * DM + 64 + tid];
    float s = v0 + v1;
    #pragma unroll
    for (int o = 32; o; o >>= 1) s += __shfl_xor(s, o);
    float mu = s * (1.f / 128.f);
    float d0 = v0 - mu, d1 = v1 - mu;
    float q = d0 * d0 + d1 * d1;
    #pragma unroll
    for (int o = 32; o; o >>= 1) q += __shfl_xor(q, o);
    float rstd = rsqrtf(q * (1.f / 128.f) + 1e-5f);
    hn[(size_t)row * DM + tid]      = d0 * rstd * lnw[layer*DM + tid]      + lnb[layer*DM + tid];
    hn[(size_t)row * DM + 64 + tid] = d1 * rstd * lnw[layer*DM + 64 + tid] + lnb[layer*DM + 64 + tid];
}

// ---------------- causal conv(4) + SiLU, plus dt ----------------
__global__ void conv_kernel(const float* __restrict__ zx, const float* __restrict__ convw,
                            const float* __restrict__ convb, const float* __restrict__ dt_bias,
                            float* __restrict__ xc, float* __restrict__ dtb, int layer) {
    int row = blockIdx.x;  // token
    int c = threadIdx.x;   // 384
    int l = row & (SEQ - 1);
    const float* cw = convw + (size_t)layer * 4 * CDIM;
    float acc = convb[layer * CDIM + c];
    #pragma unroll
    for (int k = 0; k < 4; k++) {
        int dl = l + k - 3;
        if (dl >= 0) acc += cw[k * CDIM + c] * zx[(size_t)(row + k - 3) * DIP + DI + c];
    }
    float sv = acc / (1.f + expf(-acc));
    xc[(size_t)row * CDIM + c] = sv;
    if (c < NH) {
        float raw = zx[(size_t)row * DIP + DI + CDIM + c] + dt_bias[layer * NH + c];
        float dt = (raw > 20.f) ? raw : log1pf(expf(raw));
        dtb[row * NH + c] = dt;
    }
}

// ---------------- chunk A: per-chunk local end-state + decay ----------------
__global__ void chunk_state_kernel(const float* __restrict__ xc, const float* __restrict__ dtb,
                                   const float* __restrict__ A_log, float* __restrict__ Sloc,
                                   float* __restrict__ decay, int layer) {
    __shared__ float xh_s[CHUNK][HD];
    __shared__ float B_s[CHUNK][DST];
    __shared__ float wst[CHUNK];
    int bid = blockIdx.x;
    int c  = bid & (NCHUNK - 1);
    int hh = (bid >> 4) & (NH - 1);
    int b  = bid >> 6;
    int tid = threadIdx.x;
    int row0 = b * SEQ + c * CHUNK;
    float A = -expf(A_log[layer * NH + hh]);

    for (int idx = tid; idx < CHUNK * 64; idx += 256) {
        int t = idx >> 6, col = idx & 63;
        const float* xr = xc + (size_t)(row0 + t) * CDIM;
        xh_s[t][col] = xr[hh * HD + col];
        B_s[t][col]  = xr[DI + col];
    }
    if (tid < CHUNK) {
        float dtv = dtb[(row0 + tid) * NH + hh];
        float l = dtv * A;
        #pragma unroll
        for (int o = 1; o < 64; o <<= 1) { float v = __shfl_up(l, o); if (tid >= o) l += v; }
        float Ltot = __shfl(l, 63);
        wst[tid] = expf(Ltot - l) * dtv;
        if (tid == 63) decay[bid] = expf(Ltot);
    }
    __syncthreads();

    int p = tid & 63;
    int n0 = (tid >> 6) * 16;
    float s[16];
    #pragma unroll
    for (int j = 0; j < 16; j++) s[j] = 0.f;
    for (int t = 0; t < CHUNK; t++) {
        float xv = xh_s[t][p] * wst[t];
        #pragma unroll
        for (int j = 0; j < 16; j++) s[j] += xv * B_s[t][n0 + j];
    }
    float* Sp = Sloc + (size_t)bid * (HD * DST);
    #pragma unroll
    for (int j = 0; j < 16; j++) Sp[(n0 + j) * 64 + p] = s[j];  // layout [n][p]
}

// ---------------- chunk B: inter-chunk recurrence (16 steps) ----------------
__global__ void chunk_scan_kernel(const float* __restrict__ Sloc, const float* __restrict__ decay,
                                  float* __restrict__ hstart) {
    int bh = blockIdx.x;
    int tid = threadIdx.x;
    float hreg[16];
    #pragma unroll
    for (int k = 0; k < 16; k++) hreg[k] = 0.f;
    for (int c = 0; c < NCHUNK; c++) {
        size_t base = ((size_t)bh * NCHUNK + c) * (HD * DST);
        float d = decay[bh * NCHUNK + c];
        #pragma unroll
        for (int k = 0; k < 16; k++) {
            int i = tid + k * 256;
            hstart[base + i] = hreg[k];
            hreg[k] = d * hreg[k] + Sloc[base + i];
        }
    }
}

// ---------------- chunk C: outputs ----------------
__global__ void chunk_out_kernel(const float* __restrict__ xc, const float* __restrict__ dtb,
                                 const float* __restrict__ A_log, const float* __restrict__ Dpw,
                                 const float* __restrict__ hstart, float* __restrict__ y, int layer) {
    __shared__ float xh_s[CHUNK][HD];
    __shared__ float BG[CHUNK][DST + 1];
    __shared__ float C_s[CHUNK][DST];
    __shared__ float hst[DST][HD];
    __shared__ float Ls[CHUNK], dts[CHUNK];
    int bid = blockIdx.x;
    int c  = bid & (NCHUNK - 1);
    int hh = (bid >> 4) & (NH - 1);
    int b  = bid >> 6;
    int tid = threadIdx.x;
    int row0 = b * SEQ + c * CHUNK;
    float A = -expf(A_log[layer * NH + hh]);
    float Dph = Dpw[layer * NH + hh];

    for (int idx = tid; idx < CHUNK * 64; idx += 256) {
        int t = idx >> 6, col = idx & 63;
        const float* xr = xc + (size_t)(row0 + t) * CDIM;
        xh_s[t][col] = xr[hh * HD + col];
        BG[t][col]   = xr[DI + col];
        C_s[t][col]  = xr[DI + DST + col];
    }
    {
        const float* hs = hstart + (size_t)bid * (HD * DST);
        for (int idx = tid; idx < HD * DST; idx += 256)
            ((float*)hst)[idx] = hs[idx];
    }
    if (tid < CHUNK) {
        float dtv = dtb[(row0 + tid) * NH + hh];
        float l = dtv * A;
        #pragma unroll
        for (int o = 1; o < 64; o <<= 1) { float v = __shfl_up(l, o); if (tid >= o) l += v; }
        Ls[tid] = l;
        dts[tid] = dtv;
    }
    __syncthreads();

    float g[16];
    #pragma unroll
    for (int k = 0; k < 16; k++) {
        int i = tid + k * 256;
        int t = i >> 6, s = i & 63;
        float mv = 0.f;
        if (s <= t) {
            #pragma unroll 16
            for (int n = 0; n < DST; n++) mv += C_s[t][n] * BG[s][n];
            mv *= expf(Ls[t] - Ls[s]) * dts[s];
        }
        g[k] = mv;
    }
    __syncthreads();
    #pragma unroll
    for (int k = 0; k < 16; k++) {
        int i = tid + k * 256;
        int t = i >> 6, s = i & 63;
        BG[t][s] = g[k];
    }
    __syncthreads();

    int p = tid & 63;
    int tg = tid >> 6;
    for (int j = 0; j < 16; j++) {
        int t = tg * 16 + j;
        float acc = Dph * xh_s[t][p];
        float sv = 0.f;
        #pragma unroll 16
        for (int n = 0; n < DST; n++) sv += C_s[t][n] * hst[n][p];
        acc += expf(Ls[t]) * sv;
        float iv = 0.f;
        #pragma unroll 16
        for (int s = 0; s < CHUNK; s++) iv += BG[t][s] * xh_s[s][p];
        acc += iv;
        y[(size_t)(row0 + t) * DI + hh * HD + p] = acc;
    }
}

// ---------------- gate (silu(z)) + RMSNorm over 256 ----------------
__global__ void gaterms_kernel(const float* __restrict__ zx, const float* __restrict__ rmsw,
                               float* __restrict__ y, int layer) {
    int row = blockIdx.x; int c = threadIdx.x; // 256
    float z = zx[(size_t)row * DIP + c];
    float g = z / (1.f + expf(-z));
    float v = y[(size_t)row * DI + c] * g;
    float q = v * v;
    #pragma unroll
    for (int o = 32; o; o >>= 1) q += __shfl_xor(q, o);
    __shared__ float sred[4];
    if ((c & 63) == 0) sred[c >> 6] = q;
    __syncthreads();
    float tot = sred[0] + sred[1] + sred[2] + sred[3];
    float rstd = rsqrtf(tot * (1.f / 256.f) + 1e-5f);
    y[(size_t)row * DI + c] = v * rstd * rmsw[layer * DI + c];
}

// ---------------- fc2b ----------------
__global__ void fc2b_kernel(const float* __restrict__ h2, const float* __restrict__ W,
                            const float* __restrict__ bias, float* __restrict__ out) {
    int idx = blockIdx.x * 256 + threadIdx.x;   // 98304 total
    int row = idx / 6, c = idx % 6;
    float acc = bias[c];
    const float* hr = h2 + (size_t)row * DM;
    #pragma unroll 16
    for (int k = 0; k < DM; k++) acc += hr[k] * W[k * 6 + c];
    out[idx] = acc;
}

extern "C" void kernel_launch(void* const* d_in, const int* in_sizes, int n_in,
                              void* d_out, int out_size, void* d_ws, size_t ws_size,
                              hipStream_t stream) {
    const float* x       = (const float*)d_in[0];
    const float* fc1_W   = (const float*)d_in[1];
    const float* fc1_b   = (const float*)d_in[2];
    const float* ln_w    = (const float*)d_in[3];
    const float* ln_b    = (const float*)d_in[4];
    const float* in_W    = (const float*)d_in[5];
    const float* conv_w  = (const float*)d_in[6];
    const float* conv_b  = (const float*)d_in[7];
    const float* dt_bias = (const float*)d_in[8];
    const float* A_log   = (const float*)d_in[9];
    const float* Dp      = (const float*)d_in[10];
    const float* rms_w   = (const float*)d_in[11];
    const float* out_W   = (const float*)d_in[12];
    const float* fc2_W1  = (const float*)d_in[13];
    const float* fc2_b1  = (const float*)d_in[14];
    const float* fc2_W2  = (const float*)d_in[15];
    const float* fc2_b2  = (const float*)d_in[16];
    float* out = (float*)d_out;

    float* ws = (float*)d_ws;
    float* h     = ws;                          // 16384*128
    float* hn    = h     + (size_t)NROWS * DM;
    float* zx    = hn    + (size_t)NROWS * DM;  // 16384*644
    float* xc    = zx    + (size_t)NROWS * DIP; // 16384*384
    float* dtb   = xc    + (size_t)NROWS * CDIM;// 16384*4
    float* yb    = dtb   + (size_t)NROWS * NH;  // 16384*256
    float* h2    = yb    + (size_t)NROWS * DI;  // 16384*128
    float* Sloc  = h2    + (size_t)NROWS * DM;  // 1024*4096
    float* hstr  = Sloc  + (size_t)BATCH*NH*NCHUNK*HD*DST;
    float* decay = hstr  + (size_t)BATCH*NH*NCHUNK*HD*DST; // 1024

    fc1_mfma<<<NROWS / 64, 512, 0, stream>>>(x, fc1_W, fc1_b, h);

    for (int layer = 0; layer < 2; layer++) {
        ln_kernel<<<NROWS, 64, 0, stream>>>(h, ln_w, ln_b, hn, layer);
        inproj_mfma<<<dim3(NROWS / 64, 6), 512, 0, stream>>>(hn, in_W, zx, layer);
        conv_kernel<<<NROWS, CDIM, 0, stream>>>(zx, conv_w, conv_b, dt_bias, xc, dtb, layer);
        chunk_state_kernel<<<BATCH*NH*NCHUNK, 256, 0, stream>>>(xc, dtb, A_log, Sloc, decay, layer);
        chunk_scan_kernel<<<BATCH*NH, 256, 0, stream>>>(Sloc, decay, hstr);
        chunk_out_kernel<<<BATCH*NH*NCHUNK, 256, 0, stream>>>(xc, dtb, A_log, Dp, hstr, yb, layer);
        gaterms_kernel<<<NROWS, 256, 0, stream>>>(zx, rms_w, yb, layer);
        outproj_mfma<<<NROWS / 64, 512, 0, stream>>>(yb, out_W, h, layer);
    }

    fc2a_mfma<<<NROWS / 64, 512, 0, stream>>>(h, fc2_W1, fc2_b1, h2);
    fc2b_kernel<<<NROWS * 6 / 256, 256, 0, stream>>>(h2, fc2_W2, fc2_b2, out);
}

// Round 5
// 463.842 us; speedup vs baseline: 7.2576x; 1.3602x over previous
//
#include <hip/hip_runtime.h>
#include <hip/hip_bf16.h>

// Dims
#define BATCH 16
#define SEQ 1024
#define NROWS (BATCH*SEQ)          // 16384 tokens
#define IN_DIM 768
#define DM 128
#define DIP 644
#define DI 256
#define CDIM 384
#define DST 64
#define NH 4
#define HD 64
#define CHUNK 64
#define NCHUNK (SEQ/CHUNK)         // 16

typedef __attribute__((ext_vector_type(8))) short short8;
typedef __attribute__((ext_vector_type(4))) float float4v;

// f32 -> bf16 (RNE) as raw short
__device__ __forceinline__ short f2b(float f) {
    unsigned u = __builtin_bit_cast(unsigned, f);
    u += 0x7fffu + ((u >> 16) & 1u);
    return (short)(u >> 16);
}
// raw bf16 short -> f32
__device__ __forceinline__ float s2f(short s) {
    unsigned u = ((unsigned)(unsigned short)s) << 16;
    return __builtin_bit_cast(float, u);
}

// ============================================================
// Generic MFMA GEMM tile pattern (block 512 = 8 waves, M=64 x N=128)
// ============================================================
#define GEMM_PROLOGUE() \
    int tid = threadIdx.x; \
    int lane = tid & 63; \
    int m = lane & 15; \
    int kq = (lane >> 4) * 8; \
    int w = tid >> 6; \
    int mrow = (w & 3) * 16; \
    int ngrp = w >> 2; \
    int a_off = (mrow + m) * 72 + kq; \
    int b_off = (ngrp * 64 + m) * 72 + kq; \
    float4v acc[4]; \
    acc[0] = (float4v)0.f; acc[1] = (float4v)0.f; acc[2] = (float4v)0.f; acc[3] = (float4v)0.f;

#define GEMM_STAGE_A(srcptr, LDA, row0, k0) \
    for (int idx = tid; idx < 64 * 64; idx += 512) { \
        int r = idx >> 6, k = idx & 63; \
        As[r * 72 + k] = f2b(srcptr[(size_t)((row0) + r) * (LDA) + (k0) + k]); \
    }

#define GEMM_COMPUTE_TILE() \
    { \
        short8 a0 = *reinterpret_cast<const short8*>(&As[a_off]); \
        short8 a1 = *reinterpret_cast<const short8*>(&As[a_off + 32]); \
        _Pragma("unroll") \
        for (int nt = 0; nt < 4; nt++) { \
            short8 b0 = *reinterpret_cast<const short8*>(&Bt[b_off + nt * 16 * 72]); \
            short8 b1 = *reinterpret_cast<const short8*>(&Bt[b_off + nt * 16 * 72 + 32]); \
            acc[nt] = __builtin_amdgcn_mfma_f32_16x16x32_bf16(a0, b0, acc[nt], 0, 0, 0); \
            acc[nt] = __builtin_amdgcn_mfma_f32_16x16x32_bf16(a1, b1, acc[nt], 0, 0, 0); \
        } \
    }

// ---------------- fc1 (MFMA): x@W(768,128)+b+PE -> h ----------------
__global__ __launch_bounds__(512) void fc1_mfma(const float* __restrict__ x,
                                                const float* __restrict__ W,
                                                const float* __restrict__ bias,
                                                float* __restrict__ h) {
    __shared__ short As[64 * 72];
    __shared__ short Bt[128 * 72];
    GEMM_PROLOGUE();
    int row0 = blockIdx.x * 64;
    for (int kt = 0; kt < 12; kt++) {
        int k0 = kt * 64;
        if (kt) __syncthreads();
        GEMM_STAGE_A(x, IN_DIM, row0, k0);
        for (int idx = tid; idx < 64 * 128; idx += 512) {
            int kk = idx >> 7, n = idx & 127;
            Bt[n * 72 + kk] = f2b(W[(size_t)(k0 + kk) * DM + n]);
        }
        __syncthreads();
        GEMM_COMPUTE_TILE();
    }
    #pragma unroll
    for (int nt = 0; nt < 4; nt++) {
        int col = ngrp * 64 + nt * 16 + m;
        float bv = bias[col];
        float div = expf(-(float)(col & ~1) * 0.071955784f);
        #pragma unroll
        for (int r = 0; r < 4; r++) {
            int row = row0 + mrow + (lane >> 4) * 4 + r;
            int t = row & (SEQ - 1);
            float arg = (float)t * div;
            float pe = (col & 1) ? cosf(arg) : sinf(arg);
            h[(size_t)row * DM + col] = acc[nt][r] + bv + pe;
        }
    }
}

// ---------------- in_proj with fused LayerNorm ----------------
__global__ __launch_bounds__(512) void inproj_ln_mfma(const float* __restrict__ h,
                                                      const float* __restrict__ lnw,
                                                      const float* __restrict__ lnb,
                                                      const float* __restrict__ W,
                                                      float* __restrict__ zx, int layer) {
    __shared__ short As[64 * 72];
    __shared__ short Bt[128 * 72];
    __shared__ float mu_s[64], rs_s[64];
    GEMM_PROLOGUE();
    int row0 = blockIdx.x * 64;
    int ncol0 = blockIdx.y * 128;
    const float* Wl = W + (size_t)layer * DM * DIP;
    // LN stats: 8 threads per row, 16 elems each
    {
        int r = tid >> 3, j = tid & 7;
        const float* hr = h + (size_t)(row0 + r) * DM + j * 16;
        float s1 = 0.f, s2 = 0.f;
        #pragma unroll
        for (int i = 0; i < 16; i++) { float v = hr[i]; s1 += v; s2 += v * v; }
        #pragma unroll
        for (int o = 1; o < 8; o <<= 1) { s1 += __shfl_xor(s1, o); s2 += __shfl_xor(s2, o); }
        if (j == 0) {
            float mu = s1 * (1.f / 128.f);
            mu_s[r] = mu;
            rs_s[r] = rsqrtf(s2 * (1.f / 128.f) - mu * mu + 1e-5f);
        }
    }
    __syncthreads();
    for (int kt = 0; kt < 2; kt++) {
        int k0 = kt * 64;
        if (kt) __syncthreads();
        for (int idx = tid; idx < 64 * 64; idx += 512) {
            int r = idx >> 6, k = idx & 63; int kk = k0 + k;
            float v = h[(size_t)(row0 + r) * DM + kk];
            As[r * 72 + k] = f2b((v - mu_s[r]) * rs_s[r] * lnw[layer * DM + kk] + lnb[layer * DM + kk]);
        }
        for (int idx = tid; idx < 64 * 128; idx += 512) {
            int kk = idx >> 7, n = idx & 127;
            int col = ncol0 + n;
            Bt[n * 72 + kk] = (col < DIP) ? f2b(Wl[(size_t)(k0 + kk) * DIP + col]) : (short)0;
        }
        __syncthreads();
        GEMM_COMPUTE_TILE();
    }
    #pragma unroll
    for (int nt = 0; nt < 4; nt++) {
        int col = ncol0 + ngrp * 64 + nt * 16 + m;
        if (col < DIP) {
            #pragma unroll
            for (int r = 0; r < 4; r++) {
                int row = row0 + mrow + (lane >> 4) * 4 + r;
                zx[(size_t)row * DIP + col] = acc[nt][r];
            }
        }
    }
}

// ---------------- causal conv(4) + SiLU, plus dt ----------------
__global__ void conv_kernel(const float* __restrict__ zx, const float* __restrict__ convw,
                            const float* __restrict__ convb, const float* __restrict__ dt_bias,
                            float* __restrict__ xc, float* __restrict__ dtb, int layer) {
    int row = blockIdx.x;  // token
    int c = threadIdx.x;   // 384
    int l = row & (SEQ - 1);
    const float* cw = convw + (size_t)layer * 4 * CDIM;
    float acc = convb[layer * CDIM + c];
    #pragma unroll
    for (int k = 0; k < 4; k++) {
        int dl = l + k - 3;
        if (dl >= 0) acc += cw[k * CDIM + c] * zx[(size_t)(row + k - 3) * DIP + DI + c];
    }
    float sv = acc / (1.f + expf(-acc));
    xc[(size_t)row * CDIM + c] = sv;
    if (c < NH) {
        float raw = zx[(size_t)row * DIP + DI + CDIM + c] + dt_bias[layer * NH + c];
        float dt = (raw > 20.f) ? raw : log1pf(expf(raw));
        dtb[row * NH + c] = dt;
    }
}

// ---------------- chunk A (MFMA): S[p][n] = sum_t w[t]*x[t][p]*B[t][n] ----------------
__global__ __launch_bounds__(256) void chunk_state_mfma(const float* __restrict__ xc,
                                                        const float* __restrict__ dtb,
                                                        const float* __restrict__ A_log,
                                                        float* __restrict__ Sloc,
                                                        float* __restrict__ decay, int layer) {
    __shared__ short XTw[64 * 72];   // [p][t] = x[t][p]*wst[t]
    __shared__ short BT[64 * 72];    // [n][t] = B[t][n]
    __shared__ float wst[64];
    int bid = blockIdx.x;
    int c  = bid & (NCHUNK - 1);
    int hh = (bid >> 4) & (NH - 1);
    int b  = bid >> 6;
    int tid = threadIdx.x;
    int row0 = b * SEQ + c * CHUNK;
    float A = -expf(A_log[layer * NH + hh]);

    if (tid < CHUNK) {
        float dtv = dtb[(row0 + tid) * NH + hh];
        float l = dtv * A;
        #pragma unroll
        for (int o = 1; o < 64; o <<= 1) { float v = __shfl_up(l, o); if (tid >= o) l += v; }
        float Ltot = __shfl(l, 63);
        wst[tid] = expf(Ltot - l) * dtv;
        if (tid == 63) decay[bid] = expf(Ltot);
    }
    __syncthreads();
    for (int idx = tid; idx < CHUNK * 64; idx += 256) {
        int t = idx >> 6, cc = idx & 63;
        const float* xr = xc + (size_t)(row0 + t) * CDIM;
        XTw[cc * 72 + t] = f2b(xr[hh * HD + cc] * wst[t]);
        BT [cc * 72 + t] = f2b(xr[DI + cc]);
    }
    __syncthreads();

    int lane = tid & 63;
    int m = lane & 15;
    int kq = (lane >> 4) * 8;
    int w = tid >> 6;               // 4 waves: p-rows w*16..+15
    int a_off = (w * 16 + m) * 72 + kq;
    float4v acc[4];
    acc[0] = (float4v)0.f; acc[1] = (float4v)0.f; acc[2] = (float4v)0.f; acc[3] = (float4v)0.f;
    short8 a0 = *reinterpret_cast<const short8*>(&XTw[a_off]);
    short8 a1 = *reinterpret_cast<const short8*>(&XTw[a_off + 32]);
    #pragma unroll
    for (int nt = 0; nt < 4; nt++) {
        int bo = (nt * 16 + m) * 72 + kq;
        short8 b0 = *reinterpret_cast<const short8*>(&BT[bo]);
        short8 b1 = *reinterpret_cast<const short8*>(&BT[bo + 32]);
        acc[nt] = __builtin_amdgcn_mfma_f32_16x16x32_bf16(a0, b0, acc[nt], 0, 0, 0);
        acc[nt] = __builtin_amdgcn_mfma_f32_16x16x32_bf16(a1, b1, acc[nt], 0, 0, 0);
    }
    float* Sp = Sloc + (size_t)bid * (HD * DST);
    int tq = (lane >> 4) * 4;
    #pragma unroll
    for (int nt = 0; nt < 4; nt++) {
        #pragma unroll
        for (int r = 0; r < 4; r++) {
            int p = w * 16 + tq + r;
            int n = nt * 16 + m;
            Sp[p * DST + n] = acc[nt][r];   // layout [p][n]
        }
    }
}

// ---------------- chunk B: inter-chunk recurrence (flat [p][n]) ----------------
__global__ void chunk_scan_kernel(const float* __restrict__ Sloc, const float* __restrict__ decay,
                                  float* __restrict__ hstart) {
    int bh = blockIdx.x;
    int tid = threadIdx.x;
    float hreg[16];
    #pragma unroll
    for (int k = 0; k < 16; k++) hreg[k] = 0.f;
    for (int c = 0; c < NCHUNK; c++) {
        size_t base = ((size_t)bh * NCHUNK + c) * (HD * DST);
        float d = decay[bh * NCHUNK + c];
        #pragma unroll
        for (int k = 0; k < 16; k++) {
            int i = tid + k * 256;
            hstart[base + i] = hreg[k];
            hreg[k] = d * hreg[k] + Sloc[base + i];
        }
    }
}

// ---------------- chunk C (MFMA): outputs ----------------
__global__ __launch_bounds__(256) void chunk_out_mfma(const float* __restrict__ xc,
                                                      const float* __restrict__ dtb,
                                                      const float* __restrict__ A_log,
                                                      const float* __restrict__ Dpw,
                                                      const float* __restrict__ hstart,
                                                      float* __restrict__ y, int layer) {
    __shared__ short Cb[64 * 72];    // [t][n]
    __shared__ short Bb[64 * 72];    // [s][n], later M[t][s]
    __shared__ short XT[64 * 72];    // [p][t]
    __shared__ short HT[64 * 72];    // [p][n]
    __shared__ float Ls[64], dts[64];
    int bid = blockIdx.x;
    int c  = bid & (NCHUNK - 1);
    int hh = (bid >> 4) & (NH - 1);
    int b  = bid >> 6;
    int tid = threadIdx.x;
    int row0 = b * SEQ + c * CHUNK;
    float A = -expf(A_log[layer * NH + hh]);
    float Dph = Dpw[layer * NH + hh];

    if (tid < CHUNK) {
        float dtv = dtb[(row0 + tid) * NH + hh];
        float l = dtv * A;
        #pragma unroll
        for (int o = 1; o < 64; o <<= 1) { float v = __shfl_up(l, o); if (tid >= o) l += v; }
        Ls[tid] = l;
        dts[tid] = dtv;
    }
    for (int idx = tid; idx < CHUNK * 64; idx += 256) {
        int t = idx >> 6, cc = idx & 63;
        const float* xr = xc + (size_t)(row0 + t) * CDIM;
        XT[cc * 72 + t] = f2b(xr[hh * HD + cc]);
        Bb[t * 72 + cc] = f2b(xr[DI + cc]);
        Cb[t * 72 + cc] = f2b(xr[DI + DST + cc]);
    }
    {
        const float* hs = hstart + (size_t)bid * (HD * DST);   // [p][n]
        for (int idx = tid; idx < HD * DST; idx += 256) {
            int p = idx >> 6, n = idx & 63;
            HT[p * 72 + n] = f2b(hs[p * DST + n]);
        }
    }
    __syncthreads();

    int lane = tid & 63;
    int m = lane & 15;
    int kq = (lane >> 4) * 8;
    int w = tid >> 6;                // wave w owns t-rows w*16..+15
    int tq = (lane >> 4) * 4;
    int a_off = (w * 16 + m) * 72 + kq;

    short8 ca0 = *reinterpret_cast<const short8*>(&Cb[a_off]);
    short8 ca1 = *reinterpret_cast<const short8*>(&Cb[a_off + 32]);

    // op1: G[t][s] = C . B^T     op3: inter_raw[t][p] = C . hstart^T
    float4v g[4], ir[4];
    #pragma unroll
    for (int i = 0; i < 4; i++) { g[i] = (float4v)0.f; ir[i] = (float4v)0.f; }
    #pragma unroll
    for (int st = 0; st < 4; st++) {
        int bo = (st * 16 + m) * 72 + kq;
        short8 b0 = *reinterpret_cast<const short8*>(&Bb[bo]);
        short8 b1 = *reinterpret_cast<const short8*>(&Bb[bo + 32]);
        g[st] = __builtin_amdgcn_mfma_f32_16x16x32_bf16(ca0, b0, g[st], 0, 0, 0);
        g[st] = __builtin_amdgcn_mfma_f32_16x16x32_bf16(ca1, b1, g[st], 0, 0, 0);
        short8 h0 = *reinterpret_cast<const short8*>(&HT[bo]);
        short8 h1 = *reinterpret_cast<const short8*>(&HT[bo + 32]);
        ir[st] = __builtin_amdgcn_mfma_f32_16x16x32_bf16(ca0, h0, ir[st], 0, 0, 0);
        ir[st] = __builtin_amdgcn_mfma_f32_16x16x32_bf16(ca1, h1, ir[st], 0, 0, 0);
    }
    __syncthreads();   // all waves done reading Bb
    // mask+decay G -> M, write into Bb as [t][s]
    #pragma unroll
    for (int st = 0; st < 4; st++) {
        #pragma unroll
        for (int r = 0; r < 4; r++) {
            int t = w * 16 + tq + r;
            int s = st * 16 + m;
            float mv = 0.f;
            if (s <= t) mv = g[st][r] * expf(Ls[t] - Ls[s]) * dts[s];
            Bb[t * 72 + s] = f2b(mv);
        }
    }
    __syncthreads();
    // op2: intra[t][p] = M . X^T  (accumulate into ir scaled later? separate acc)
    float4v yi[4];
    #pragma unroll
    for (int i = 0; i < 4; i++) yi[i] = (float4v)0.f;
    short8 ma0 = *reinterpret_cast<const short8*>(&Bb[a_off]);
    short8 ma1 = *reinterpret_cast<const short8*>(&Bb[a_off + 32]);
    #pragma unroll
    for (int pt = 0; pt < 4; pt++) {
        int bo = (pt * 16 + m) * 72 + kq;
        short8 x0 = *reinterpret_cast<const short8*>(&XT[bo]);
        short8 x1 = *reinterpret_cast<const short8*>(&XT[bo + 32]);
        yi[pt] = __builtin_amdgcn_mfma_f32_16x16x32_bf16(ma0, x0, yi[pt], 0, 0, 0);
        yi[pt] = __builtin_amdgcn_mfma_f32_16x16x32_bf16(ma1, x1, yi[pt], 0, 0, 0);
    }
    // epilogue: y = intra + exp(L[t])*inter + Dp*x   (x re-read f32 from global)
    #pragma unroll
    for (int r = 0; r < 4; r++) {
        int t = w * 16 + tq + r;
        float et = expf(Ls[t]);
        const float* xr = xc + (size_t)(row0 + t) * CDIM + hh * HD;
        float* yr = y + (size_t)(row0 + t) * DI + hh * HD;
        #pragma unroll
        for (int pt = 0; pt < 4; pt++) {
            int p = pt * 16 + m;
            yr[p] = yi[pt][r] + et * ir[pt][r] + Dph * xr[p];
        }
    }
}

// ---------------- out_proj with fused gate(silu)+RMSNorm, + residual ----------------
__global__ __launch_bounds__(512) void outproj_gate_mfma(const float* __restrict__ yb,
                                                         const float* __restrict__ zx,
                                                         const float* __restrict__ rmsw,
                                                         const float* __restrict__ W,
                                                         float* __restrict__ h, int layer) {
    __shared__ short As[64 * 72];
    __shared__ short Bt[128 * 72];
    __shared__ float rs_s[64];
    GEMM_PROLOGUE();
    int row0 = blockIdx.x * 64;
    const float* Wl = W + (size_t)layer * DI * DM;
    // RMS stats on v = y * silu(z): 8 threads/row, 32 elems each
    {
        int r = tid >> 3, j = tid & 7;
        const float* yr = yb + (size_t)(row0 + r) * DI + j * 32;
        const float* zr = zx + (size_t)(row0 + r) * DIP + j * 32;
        float s2 = 0.f;
        #pragma unroll
        for (int i = 0; i < 32; i++) {
            float z = zr[i];
            float v = yr[i] * (z / (1.f + expf(-z)));
            s2 += v * v;
        }
        #pragma unroll
        for (int o = 1; o < 8; o <<= 1) s2 += __shfl_xor(s2, o);
        if (j == 0) rs_s[r] = rsqrtf(s2 * (1.f / 256.f) + 1e-5f);
    }
    __syncthreads();
    for (int kt = 0; kt < 4; kt++) {
        int k0 = kt * 64;
        if (kt) __syncthreads();
        for (int idx = tid; idx < 64 * 64; idx += 512) {
            int r = idx >> 6, k = idx & 63; int kk = k0 + k;
            float z = zx[(size_t)(row0 + r) * DIP + kk];
            float v = yb[(size_t)(row0 + r) * DI + kk] * (z / (1.f + expf(-z)));
            As[r * 72 + k] = f2b(v * rs_s[r] * rmsw[layer * DI + kk]);
        }
        for (int idx = tid; idx < 64 * 128; idx += 512) {
            int kk = idx >> 7, n = idx & 127;
            Bt[n * 72 + kk] = f2b(Wl[(size_t)(k0 + kk) * DM + n]);
        }
        __syncthreads();
        GEMM_COMPUTE_TILE();
    }
    #pragma unroll
    for (int nt = 0; nt < 4; nt++) {
        int col = ngrp * 64 + nt * 16 + m;
        #pragma unroll
        for (int r = 0; r < 4; r++) {
            int row = row0 + mrow + (lane >> 4) * 4 + r;
            size_t i = (size_t)row * DM + col;
            h[i] = h[i] + acc[nt][r];
        }
    }
}

// ---------------- fc2a (MFMA): h@W1(128,128)+b1, leaky 0.1 -> h2 ----------------
__global__ __launch_bounds__(512) void fc2a_mfma(const float* __restrict__ h,
                                                 const float* __restrict__ W,
                                                 const float* __restrict__ bias,
                                                 float* __restrict__ h2) {
    __shared__ short As[64 * 72];
    __shared__ short Bt[128 * 72];
    GEMM_PROLOGUE();
    int row0 = blockIdx.x * 64;
    for (int kt = 0; kt < 2; kt++) {
        int k0 = kt * 64;
        if (kt) __syncthreads();
        GEMM_STAGE_A(h, DM, row0, k0);
        for (int idx = tid; idx < 64 * 128; idx += 512) {
            int kk = idx >> 7, n = idx & 127;
            Bt[n * 72 + kk] = f2b(W[(size_t)(k0 + kk) * DM + n]);
        }
        __syncthreads();
        GEMM_COMPUTE_TILE();
    }
    #pragma unroll
    for (int nt = 0; nt < 4; nt++) {
        int col = ngrp * 64 + nt * 16 + m;
        float bv = bias[col];
        #pragma unroll
        for (int r = 0; r < 4; r++) {
            int row = row0 + mrow + (lane >> 4) * 4 + r;
            float o = acc[nt][r] + bv;
            h2[(size_t)row * DM + col] = (o > 0.f) ? o : 0.1f * o;
        }
    }
}

// ---------------- fc2b ----------------
__global__ void fc2b_kernel(const float* __restrict__ h2, const float* __restrict__ W,
                            const float* __restrict__ bias, float* __restrict__ out) {
    int idx = blockIdx.x * 256 + threadIdx.x;   // 98304 total
    int row = idx / 6, c = idx % 6;
    float acc = bias[c];
    const float* hr = h2 + (size_t)row * DM;
    #pragma unroll 16
    for (int k = 0; k < DM; k++) acc += hr[k] * W[k * 6 + c];
    out[idx] = acc;
}

extern "C" void kernel_launch(void* const* d_in, const int* in_sizes, int n_in,
                              void* d_out, int out_size, void* d_ws, size_t ws_size,
                              hipStream_t stream) {
    const float* x       = (const float*)d_in[0];
    const float* fc1_W   = (const float*)d_in[1];
    const float* fc1_b   = (const float*)d_in[2];
    const float* ln_w    = (const float*)d_in[3];
    const float* ln_b    = (const float*)d_in[4];
    const float* in_W    = (const float*)d_in[5];
    const float* conv_w  = (const float*)d_in[6];
    const float* conv_b  = (const float*)d_in[7];
    const float* dt_bias = (const float*)d_in[8];
    const float* A_log   = (const float*)d_in[9];
    const float* Dp      = (const float*)d_in[10];
    const float* rms_w   = (const float*)d_in[11];
    const float* out_W   = (const float*)d_in[12];
    const float* fc2_W1  = (const float*)d_in[13];
    const float* fc2_b1  = (const float*)d_in[14];
    const float* fc2_W2  = (const float*)d_in[15];
    const float* fc2_b2  = (const float*)d_in[16];
    float* out = (float*)d_out;

    float* ws = (float*)d_ws;
    float* h     = ws;                          // 16384*128
    float* zx    = h     + (size_t)NROWS * DM;  // 16384*644
    float* xc    = zx    + (size_t)NROWS * DIP; // 16384*384
    float* dtb   = xc    + (size_t)NROWS * CDIM;// 16384*4
    float* yb    = dtb   + (size_t)NROWS * NH;  // 16384*256
    float* h2    = yb    + (size_t)NROWS * DI;  // 16384*128
    float* Sloc  = h2    + (size_t)NROWS * DM;  // 1024*4096
    float* hstr  = Sloc  + (size_t)BATCH*NH*NCHUNK*HD*DST;
    float* decay = hstr  + (size_t)BATCH*NH*NCHUNK*HD*DST; // 1024

    fc1_mfma<<<NROWS / 64, 512, 0, stream>>>(x, fc1_W, fc1_b, h);

    for (int layer = 0; layer < 2; layer++) {
        inproj_ln_mfma<<<dim3(NROWS / 64, 6), 512, 0, stream>>>(h, ln_w, ln_b, in_W, zx, layer);
        conv_kernel<<<NROWS, CDIM, 0, stream>>>(zx, conv_w, conv_b, dt_bias, xc, dtb, layer);
        chunk_state_mfma<<<BATCH*NH*NCHUNK, 256, 0, stream>>>(xc, dtb, A_log, Sloc, decay, layer);
        chunk_scan_kernel<<<BATCH*NH, 256, 0, stream>>>(Sloc, decay, hstr);
        chunk_out_mfma<<<BATCH*NH*NCHUNK, 256, 0, stream>>>(xc, dtb, A_log, Dp, hstr, yb, layer);
        outproj_gate_mfma<<<NROWS / 64, 512, 0, stream>>>(yb, zx, rms_w, out_W, h, layer);
    }

    fc2a_mfma<<<NROWS / 64, 512, 0, stream>>>(h, fc2_W1, fc2_b1, h2);
    fc2b_kernel<<<NROWS * 6 / 256, 256, 0, stream>>>(h2, fc2_W2, fc2_b2, out);
}

// Round 6
// 301.311 us; speedup vs baseline: 11.1725x; 1.5394x over previous
//
#include <hip/hip_runtime.h>
#include <hip/hip_bf16.h>

// Dims
#define BATCH 16
#define SEQ 1024
#define NROWS (BATCH*SEQ)          // 16384 tokens
#define IN_DIM 768
#define DM 128
#define DIP 644
#define DI 256
#define CDIM 384
#define DST 64
#define NH 4
#define HD 64
#define CHUNK 64
#define NCHUNK (SEQ/CHUNK)         // 16

// bf16 weight area offsets (in shorts)
#define WB_FC1   0          // [128][768]
#define WB_IN    98304      // [2][644][128]
#define WB_OUT   263168     // [2][128][256]
#define WB_FC2   328704     // [128][128]
#define WB_TOTAL 345088

typedef __attribute__((ext_vector_type(8))) short short8;
typedef __attribute__((ext_vector_type(4))) float float4v;

// f32 -> bf16 (RNE) as raw short
__device__ __forceinline__ short f2b(float f) {
    unsigned u = __builtin_bit_cast(unsigned, f);
    u += 0x7fffu + ((u >> 16) & 1u);
    return (short)(u >> 16);
}
__device__ __forceinline__ short8 pack8f(float4 a, float4 b) {
    short8 r;
    r[0] = f2b(a.x); r[1] = f2b(a.y); r[2] = f2b(a.z); r[3] = f2b(a.w);
    r[4] = f2b(b.x); r[5] = f2b(b.y); r[6] = f2b(b.z); r[7] = f2b(b.w);
    return r;
}

// ---------------- weight prep: convert + transpose to bf16 ----------------
__global__ void prep_weights(const float* __restrict__ fc1_W, const float* __restrict__ in_W,
                             const float* __restrict__ out_W, const float* __restrict__ fc2_W1,
                             short* __restrict__ wb) {
    int idx = blockIdx.x * 256 + threadIdx.x;
    if (idx < 98304) {                       // fc1_Wt[n][k] <- fc1_W[k][n]
        int n = idx / 768, k = idx % 768;
        wb[WB_FC1 + idx] = f2b(fc1_W[k * 128 + n]);
        return;
    }
    idx -= 98304;
    if (idx < 2 * 82432) {                   // in_Wt[l][n][k] <- in_W[l][k][n]
        int l = idx / 82432, r = idx % 82432;
        int n = r / 128, k = r % 128;
        wb[WB_IN + idx] = f2b(in_W[(size_t)l * 82432 + k * 644 + n]);
        return;
    }
    idx -= 164864;
    if (idx < 2 * 32768) {                   // out_Wt[l][n][k] <- out_W[l][k][n]
        int l = idx / 32768, r = idx % 32768;
        int n = r / 256, k = r % 256;
        wb[WB_OUT + idx] = f2b(out_W[(size_t)l * 32768 + k * 128 + n]);
        return;
    }
    idx -= 65536;
    if (idx < 16384) {                       // fc2_W1t[n][k] <- fc2_W1[k][n]
        int n = idx / 128, k = idx % 128;
        wb[WB_FC2 + idx] = f2b(fc2_W1[k * 128 + n]);
    }
}

// ============================================================
// MFMA GEMM tile pattern (block 512 = 8 waves, M=64 x N=128)
// ============================================================
#define GEMM_PROLOGUE() \
    int tid = threadIdx.x; \
    int lane = tid & 63; \
    int m = lane & 15; \
    int kq = (lane >> 4) * 8; \
    int w = tid >> 6; \
    int mrow = (w & 3) * 16; \
    int ngrp = w >> 2; \
    int a_off = (mrow + m) * 72 + kq; \
    int b_off = (ngrp * 64 + m) * 72 + kq; \
    int ar = tid >> 3; \
    int ak = (tid & 7) * 8; \
    (void)ar; (void)ak; \
    float4v acc[4]; \
    acc[0] = (float4v)0.f; acc[1] = (float4v)0.f; acc[2] = (float4v)0.f; acc[3] = (float4v)0.f;

#define GEMM_COMPUTE_TILE() \
    { \
        short8 a0 = *reinterpret_cast<const short8*>(&As[a_off]); \
        short8 a1 = *reinterpret_cast<const short8*>(&As[a_off + 32]); \
        _Pragma("unroll") \
        for (int nt = 0; nt < 4; nt++) { \
            short8 b0 = *reinterpret_cast<const short8*>(&Bt[b_off + nt * 16 * 72]); \
            short8 b1 = *reinterpret_cast<const short8*>(&Bt[b_off + nt * 16 * 72 + 32]); \
            acc[nt] = __builtin_amdgcn_mfma_f32_16x16x32_bf16(a0, b0, acc[nt], 0, 0, 0); \
            acc[nt] = __builtin_amdgcn_mfma_f32_16x16x32_bf16(a1, b1, acc[nt], 0, 0, 0); \
        } \
    }

// B-stage from pre-transposed bf16 weights (ld = row length in shorts)
#define GEMM_STAGE_B(wtptr, LDB, k0) \
    _Pragma("unroll") \
    for (int i = 0; i < 2; i++) { \
        int idx = tid + i * 512; \
        int n = idx >> 3, kk = (idx & 7) * 8; \
        *reinterpret_cast<short8*>(&Bt[n * 72 + kk]) = \
            *reinterpret_cast<const short8*>(&wtptr[n * (LDB) + (k0) + kk]); \
    }

// ---------------- fc1 (MFMA): x@W(768,128)+b+PE -> h ----------------
__global__ __launch_bounds__(512) void fc1_mfma(const float* __restrict__ x,
                                                const short* __restrict__ wt,
                                                const float* __restrict__ bias,
                                                float* __restrict__ h) {
    __shared__ short As[64 * 72];
    __shared__ short Bt[128 * 72];
    GEMM_PROLOGUE();
    int row0 = blockIdx.x * 64;
    for (int kt = 0; kt < 12; kt++) {
        int k0 = kt * 64;
        if (kt) __syncthreads();
        {
            const float* src = x + (size_t)(row0 + ar) * IN_DIM + k0 + ak;
            float4 v0 = *(const float4*)src;
            float4 v1 = *(const float4*)(src + 4);
            *reinterpret_cast<short8*>(&As[ar * 72 + ak]) = pack8f(v0, v1);
        }
        GEMM_STAGE_B(wt, 768, k0);
        __syncthreads();
        GEMM_COMPUTE_TILE();
    }
    #pragma unroll
    for (int nt = 0; nt < 4; nt++) {
        int col = ngrp * 64 + nt * 16 + m;
        float bv = bias[col];
        float div = expf(-(float)(col & ~1) * 0.071955784f);
        #pragma unroll
        for (int r = 0; r < 4; r++) {
            int row = row0 + mrow + (lane >> 4) * 4 + r;
            int t = row & (SEQ - 1);
            float arg = (float)t * div;
            float pe = (col & 1) ? cosf(arg) : sinf(arg);
            h[(size_t)row * DM + col] = acc[nt][r] + bv + pe;
        }
    }
}

// ---------------- in_proj with fused LayerNorm ----------------
__global__ __launch_bounds__(512) void inproj_ln_mfma(const float* __restrict__ h,
                                                      const float* __restrict__ lnw,
                                                      const float* __restrict__ lnb,
                                                      const short* __restrict__ wb,
                                                      float* __restrict__ zx, int layer) {
    __shared__ short As[64 * 72];
    __shared__ short Bt[128 * 72];
    __shared__ float mu_s[64], rs_s[64];
    GEMM_PROLOGUE();
    int row0 = blockIdx.x * 64;
    int ncol0 = blockIdx.y * 128;
    const short* wt = wb + WB_IN + (size_t)layer * 82432;
    {   // LN stats: 8 threads/row, 16 elems each (float4)
        int r = tid >> 3, j = tid & 7;
        const float4* hr = (const float4*)(h + (size_t)(row0 + r) * DM + j * 16);
        float s1 = 0.f, s2 = 0.f;
        #pragma unroll
        for (int i = 0; i < 4; i++) {
            float4 v = hr[i];
            s1 += v.x + v.y + v.z + v.w;
            s2 += v.x * v.x + v.y * v.y + v.z * v.z + v.w * v.w;
        }
        #pragma unroll
        for (int o = 1; o < 8; o <<= 1) { s1 += __shfl_xor(s1, o); s2 += __shfl_xor(s2, o); }
        if (j == 0) {
            float mu = s1 * (1.f / 128.f);
            mu_s[r] = mu;
            rs_s[r] = rsqrtf(s2 * (1.f / 128.f) - mu * mu + 1e-5f);
        }
    }
    __syncthreads();
    for (int kt = 0; kt < 2; kt++) {
        int k0 = kt * 64;
        if (kt) __syncthreads();
        {
            int k = k0 + ak;
            const float* src = h + (size_t)(row0 + ar) * DM + k;
            float4 v0 = *(const float4*)src;
            float4 v1 = *(const float4*)(src + 4);
            float4 w0 = *(const float4*)(lnw + layer * DM + k);
            float4 w1 = *(const float4*)(lnw + layer * DM + k + 4);
            float4 b0 = *(const float4*)(lnb + layer * DM + k);
            float4 b1 = *(const float4*)(lnb + layer * DM + k + 4);
            float mu = mu_s[ar], rs = rs_s[ar];
            v0.x = (v0.x - mu) * rs * w0.x + b0.x; v0.y = (v0.y - mu) * rs * w0.y + b0.y;
            v0.z = (v0.z - mu) * rs * w0.z + b0.z; v0.w = (v0.w - mu) * rs * w0.w + b0.w;
            v1.x = (v1.x - mu) * rs * w1.x + b1.x; v1.y = (v1.y - mu) * rs * w1.y + b1.y;
            v1.z = (v1.z - mu) * rs * w1.z + b1.z; v1.w = (v1.w - mu) * rs * w1.w + b1.w;
            *reinterpret_cast<short8*>(&As[ar * 72 + ak]) = pack8f(v0, v1);
        }
        #pragma unroll
        for (int i = 0; i < 2; i++) {
            int idx = tid + i * 512;
            int n = idx >> 3, kk = (idx & 7) * 8;
            int col = ncol0 + n;
            short8 bv = (short8)0;
            if (col < DIP) bv = *reinterpret_cast<const short8*>(&wt[col * 128 + k0 + kk]);
            *reinterpret_cast<short8*>(&Bt[n * 72 + kk]) = bv;
        }
        __syncthreads();
        GEMM_COMPUTE_TILE();
    }
    #pragma unroll
    for (int nt = 0; nt < 4; nt++) {
        int col = ncol0 + ngrp * 64 + nt * 16 + m;
        if (col < DIP) {
            #pragma unroll
            for (int r = 0; r < 4; r++) {
                int row = row0 + mrow + (lane >> 4) * 4 + r;
                zx[(size_t)row * DIP + col] = acc[nt][r];
            }
        }
    }
}

// ---------------- causal conv(4) + SiLU + dt, 4 tokens/block ----------------
__global__ void conv_kernel(const float* __restrict__ zx, const float* __restrict__ convw,
                            const float* __restrict__ convb, const float* __restrict__ dt_bias,
                            float* __restrict__ xc, float* __restrict__ dtb, int layer) {
    int c = threadIdx.x;            // 384
    int row0 = blockIdx.x * 4;
    int l0 = row0 & (SEQ - 1);
    const float* cw = convw + (size_t)layer * 4 * CDIM;
    float w0 = cw[c], w1 = cw[CDIM + c], w2 = cw[2 * CDIM + c], w3 = cw[3 * CDIM + c];
    float bb = convb[layer * CDIM + c];
    float v[7];
    #pragma unroll
    for (int i = 0; i < 7; i++) {
        int rr = row0 + i - 3;
        v[i] = (l0 + i - 3 >= 0) ? zx[(size_t)rr * DIP + DI + c] : 0.f;
    }
    #pragma unroll
    for (int j = 0; j < 4; j++) {
        float acc = bb + w0 * v[j] + w1 * v[j + 1] + w2 * v[j + 2] + w3 * v[j + 3];
        float sv = acc / (1.f + expf(-acc));
        xc[(size_t)(row0 + j) * CDIM + c] = sv;
    }
    if (c < 16) {
        int j = c >> 2, hh = c & 3;
        int row = row0 + j;
        float raw = zx[(size_t)row * DIP + DI + CDIM + hh] + dt_bias[layer * NH + hh];
        float dt = (raw > 20.f) ? raw : log1pf(expf(raw));
        dtb[row * NH + hh] = dt;
    }
}

// ---------------- chunk A (MFMA): S[p][n] ----------------
__global__ __launch_bounds__(256) void chunk_state_mfma(const float* __restrict__ xc,
                                                        const float* __restrict__ dtb,
                                                        const float* __restrict__ A_log,
                                                        float* __restrict__ Sloc,
                                                        float* __restrict__ decay, int layer) {
    __shared__ short XTw[64 * 72];   // [p][t]
    __shared__ short BT[64 * 72];    // [n][t]
    __shared__ float wst[64];
    int bid = blockIdx.x;
    int c  = bid & (NCHUNK - 1);
    int hh = (bid >> 4) & (NH - 1);
    int b  = bid >> 6;
    int tid = threadIdx.x;
    int row0 = b * SEQ + c * CHUNK;
    float A = -expf(A_log[layer * NH + hh]);

    if (tid < CHUNK) {
        float dtv = dtb[(row0 + tid) * NH + hh];
        float l = dtv * A;
        #pragma unroll
        for (int o = 1; o < 64; o <<= 1) { float v = __shfl_up(l, o); if (tid >= o) l += v; }
        float Ltot = __shfl(l, 63);
        wst[tid] = expf(Ltot - l) * dtv;
        if (tid == 63) decay[bid] = expf(Ltot);
    }
    __syncthreads();
    {
        int p = tid & 63;
        int tb0 = tid >> 6;
        #pragma unroll
        for (int i = 0; i < 2; i++) {
            int t0 = (tb0 + i * 4) * 8;
            short8 xv, bv;
            #pragma unroll
            for (int j = 0; j < 8; j++) {
                int t = t0 + j;
                const float* xr = xc + (size_t)(row0 + t) * CDIM;
                xv[j] = f2b(xr[hh * HD + p] * wst[t]);
                bv[j] = f2b(xr[DI + p]);
            }
            *reinterpret_cast<short8*>(&XTw[p * 72 + t0]) = xv;
            *reinterpret_cast<short8*>(&BT[p * 72 + t0]) = bv;
        }
    }
    __syncthreads();

    int lane = tid & 63;
    int m = lane & 15;
    int kq = (lane >> 4) * 8;
    int w = tid >> 6;
    int a_off = (w * 16 + m) * 72 + kq;
    float4v acc[4];
    acc[0] = (float4v)0.f; acc[1] = (float4v)0.f; acc[2] = (float4v)0.f; acc[3] = (float4v)0.f;
    short8 a0 = *reinterpret_cast<const short8*>(&XTw[a_off]);
    short8 a1 = *reinterpret_cast<const short8*>(&XTw[a_off + 32]);
    #pragma unroll
    for (int nt = 0; nt < 4; nt++) {
        int bo = (nt * 16 + m) * 72 + kq;
        short8 b0 = *reinterpret_cast<const short8*>(&BT[bo]);
        short8 b1 = *reinterpret_cast<const short8*>(&BT[bo + 32]);
        acc[nt] = __builtin_amdgcn_mfma_f32_16x16x32_bf16(a0, b0, acc[nt], 0, 0, 0);
        acc[nt] = __builtin_amdgcn_mfma_f32_16x16x32_bf16(a1, b1, acc[nt], 0, 0, 0);
    }
    float* Sp = Sloc + (size_t)bid * (HD * DST);
    int tq = (lane >> 4) * 4;
    #pragma unroll
    for (int nt = 0; nt < 4; nt++) {
        #pragma unroll
        for (int r = 0; r < 4; r++) {
            int p = w * 16 + tq + r;
            int n = nt * 16 + m;
            Sp[p * DST + n] = acc[nt][r];   // [p][n]
        }
    }
}

// ---------------- chunk B: inter-chunk recurrence ----------------
__global__ void chunk_scan_kernel(const float* __restrict__ Sloc, const float* __restrict__ decay,
                                  float* __restrict__ hstart) {
    int bh = blockIdx.x;
    int tid = threadIdx.x;
    float hreg[16];
    #pragma unroll
    for (int k = 0; k < 16; k++) hreg[k] = 0.f;
    for (int c = 0; c < NCHUNK; c++) {
        size_t base = ((size_t)bh * NCHUNK + c) * (HD * DST);
        float d = decay[bh * NCHUNK + c];
        #pragma unroll
        for (int k = 0; k < 16; k++) {
            int i = tid + k * 256;
            hstart[base + i] = hreg[k];
            hreg[k] = d * hreg[k] + Sloc[base + i];
        }
    }
}

// ---------------- chunk C (MFMA): outputs ----------------
__global__ __launch_bounds__(256) void chunk_out_mfma(const float* __restrict__ xc,
                                                      const float* __restrict__ dtb,
                                                      const float* __restrict__ A_log,
                                                      const float* __restrict__ Dpw,
                                                      const float* __restrict__ hstart,
                                                      float* __restrict__ y, int layer) {
    __shared__ short Cb[64 * 72];    // [t][n]
    __shared__ short Bb[64 * 72];    // [s][n], later M[t][s]
    __shared__ short XT[64 * 72];    // [p][t]
    __shared__ short HT[64 * 72];    // [p][n]
    __shared__ float Ls[64], dts[64];
    int bid = blockIdx.x;
    int c  = bid & (NCHUNK - 1);
    int hh = (bid >> 4) & (NH - 1);
    int b  = bid >> 6;
    int tid = threadIdx.x;
    int row0 = b * SEQ + c * CHUNK;
    float A = -expf(A_log[layer * NH + hh]);
    float Dph = Dpw[layer * NH + hh];

    if (tid < CHUNK) {
        float dtv = dtb[(row0 + tid) * NH + hh];
        float l = dtv * A;
        #pragma unroll
        for (int o = 1; o < 64; o <<= 1) { float v = __shfl_up(l, o); if (tid >= o) l += v; }
        Ls[tid] = l;
        dts[tid] = dtv;
    }
    {   // XT (transposed): lane-coalesced strided loads, b128 writes
        int p = tid & 63;
        int tb0 = tid >> 6;
        #pragma unroll
        for (int i = 0; i < 2; i++) {
            int t0 = (tb0 + i * 4) * 8;
            short8 xv;
            #pragma unroll
            for (int j = 0; j < 8; j++) {
                const float* xr = xc + (size_t)(row0 + t0 + j) * CDIM;
                xv[j] = f2b(xr[hh * HD + p]);
            }
            *reinterpret_cast<short8*>(&XT[p * 72 + t0]) = xv;
        }
    }
    #pragma unroll
    for (int i = 0; i < 2; i++) {   // Bb, Cb row-contiguous
        int idx = tid + i * 256;
        int t = idx >> 3, cb = (idx & 7) * 8;
        const float* xr = xc + (size_t)(row0 + t) * CDIM;
        float4 b0 = *(const float4*)(xr + DI + cb);
        float4 b1 = *(const float4*)(xr + DI + cb + 4);
        *reinterpret_cast<short8*>(&Bb[t * 72 + cb]) = pack8f(b0, b1);
        float4 c0 = *(const float4*)(xr + DI + DST + cb);
        float4 c1 = *(const float4*)(xr + DI + DST + cb + 4);
        *reinterpret_cast<short8*>(&Cb[t * 72 + cb]) = pack8f(c0, c1);
    }
    {
        const float* hs = hstart + (size_t)bid * (HD * DST);   // [p][n]
        #pragma unroll
        for (int i = 0; i < 2; i++) {
            int idx = tid + i * 256;
            int pp = idx >> 3, nb = (idx & 7) * 8;
            float4 a0 = *(const float4*)(hs + pp * 64 + nb);
            float4 a1 = *(const float4*)(hs + pp * 64 + nb + 4);
            *reinterpret_cast<short8*>(&HT[pp * 72 + nb]) = pack8f(a0, a1);
        }
    }
    __syncthreads();

    int lane = tid & 63;
    int m = lane & 15;
    int kq = (lane >> 4) * 8;
    int w = tid >> 6;
    int tq = (lane >> 4) * 4;
    int a_off = (w * 16 + m) * 72 + kq;

    short8 ca0 = *reinterpret_cast<const short8*>(&Cb[a_off]);
    short8 ca1 = *reinterpret_cast<const short8*>(&Cb[a_off + 32]);

    float4v g[4], ir[4];
    #pragma unroll
    for (int i = 0; i < 4; i++) { g[i] = (float4v)0.f; ir[i] = (float4v)0.f; }
    #pragma unroll
    for (int st = 0; st < 4; st++) {
        int bo = (st * 16 + m) * 72 + kq;
        short8 b0 = *reinterpret_cast<const short8*>(&Bb[bo]);
        short8 b1 = *reinterpret_cast<const short8*>(&Bb[bo + 32]);
        g[st] = __builtin_amdgcn_mfma_f32_16x16x32_bf16(ca0, b0, g[st], 0, 0, 0);
        g[st] = __builtin_amdgcn_mfma_f32_16x16x32_bf16(ca1, b1, g[st], 0, 0, 0);
        short8 h0 = *reinterpret_cast<const short8*>(&HT[bo]);
        short8 h1 = *reinterpret_cast<const short8*>(&HT[bo + 32]);
        ir[st] = __builtin_amdgcn_mfma_f32_16x16x32_bf16(ca0, h0, ir[st], 0, 0, 0);
        ir[st] = __builtin_amdgcn_mfma_f32_16x16x32_bf16(ca1, h1, ir[st], 0, 0, 0);
    }
    __syncthreads();
    #pragma unroll
    for (int st = 0; st < 4; st++) {
        #pragma unroll
        for (int r = 0; r < 4; r++) {
            int t = w * 16 + tq + r;
            int s = st * 16 + m;
            float mv = 0.f;
            if (s <= t) mv = g[st][r] * expf(Ls[t] - Ls[s]) * dts[s];
            Bb[t * 72 + s] = f2b(mv);
        }
    }
    __syncthreads();
    float4v yi[4];
    #pragma unroll
    for (int i = 0; i < 4; i++) yi[i] = (float4v)0.f;
    short8 ma0 = *reinterpret_cast<const short8*>(&Bb[a_off]);
    short8 ma1 = *reinterpret_cast<const short8*>(&Bb[a_off + 32]);
    #pragma unroll
    for (int pt = 0; pt < 4; pt++) {
        int bo = (pt * 16 + m) * 72 + kq;
        short8 x0 = *reinterpret_cast<const short8*>(&XT[bo]);
        short8 x1 = *reinterpret_cast<const short8*>(&XT[bo + 32]);
        yi[pt] = __builtin_amdgcn_mfma_f32_16x16x32_bf16(ma0, x0, yi[pt], 0, 0, 0);
        yi[pt] = __builtin_amdgcn_mfma_f32_16x16x32_bf16(ma1, x1, yi[pt], 0, 0, 0);
    }
    #pragma unroll
    for (int r = 0; r < 4; r++) {
        int t = w * 16 + tq + r;
        float et = expf(Ls[t]);
        const float* xr = xc + (size_t)(row0 + t) * CDIM + hh * HD;
        float* yr = y + (size_t)(row0 + t) * DI + hh * HD;
        #pragma unroll
        for (int pt = 0; pt < 4; pt++) {
            int p = pt * 16 + m;
            yr[p] = yi[pt][r] + et * ir[pt][r] + Dph * xr[p];
        }
    }
}

// ---------------- out_proj with fused gate(silu)+RMSNorm, + residual ----------------
__global__ __launch_bounds__(512) void outproj_gate_mfma(const float* __restrict__ yb,
                                                         const float* __restrict__ zx,
                                                         const float* __restrict__ rmsw,
                                                         const short* __restrict__ wb,
                                                         float* __restrict__ h, int layer) {
    __shared__ short As[64 * 72];
    __shared__ short Bt[128 * 72];
    __shared__ float rs_s[64];
    GEMM_PROLOGUE();
    int row0 = blockIdx.x * 64;
    const short* wt = wb + WB_OUT + (size_t)layer * 32768;
    {   // RMS stats on v = y*silu(z): 8 threads/row, 32 elems each
        int r = tid >> 3, j = tid & 7;
        const float4* yr = (const float4*)(yb + (size_t)(row0 + r) * DI + j * 32);
        const float4* zr = (const float4*)(zx + (size_t)(row0 + r) * DIP + j * 32);
        float s2 = 0.f;
        #pragma unroll
        for (int i = 0; i < 8; i++) {
            float4 yv = yr[i], zv = zr[i];
            float v;
            v = yv.x * (zv.x / (1.f + expf(-zv.x))); s2 += v * v;
            v = yv.y * (zv.y / (1.f + expf(-zv.y))); s2 += v * v;
            v = yv.z * (zv.z / (1.f + expf(-zv.z))); s2 += v * v;
            v = yv.w * (zv.w / (1.f + expf(-zv.w))); s2 += v * v;
        }
        #pragma unroll
        for (int o = 1; o < 8; o <<= 1) s2 += __shfl_xor(s2, o);
        if (j == 0) rs_s[r] = rsqrtf(s2 * (1.f / 256.f) + 1e-5f);
    }
    __syncthreads();
    for (int kt = 0; kt < 4; kt++) {
        int k0 = kt * 64;
        if (kt) __syncthreads();
        {
            int k = k0 + ak;
            const float* ysrc = yb + (size_t)(row0 + ar) * DI + k;
            const float* zsrc = zx + (size_t)(row0 + ar) * DIP + k;
            float4 y0 = *(const float4*)ysrc;
            float4 y1 = *(const float4*)(ysrc + 4);
            float4 z0 = *(const float4*)zsrc;
            float4 z1 = *(const float4*)(zsrc + 4);
            float4 w0 = *(const float4*)(rmsw + layer * DI + k);
            float4 w1 = *(const float4*)(rmsw + layer * DI + k + 4);
            float rs = rs_s[ar];
            y0.x = y0.x * (z0.x / (1.f + expf(-z0.x))) * rs * w0.x;
            y0.y = y0.y * (z0.y / (1.f + expf(-z0.y))) * rs * w0.y;
            y0.z = y0.z * (z0.z / (1.f + expf(-z0.z))) * rs * w0.z;
            y0.w = y0.w * (z0.w / (1.f + expf(-z0.w))) * rs * w0.w;
            y1.x = y1.x * (z1.x / (1.f + expf(-z1.x))) * rs * w1.x;
            y1.y = y1.y * (z1.y / (1.f + expf(-z1.y))) * rs * w1.y;
            y1.z = y1.z * (z1.z / (1.f + expf(-z1.z))) * rs * w1.z;
            y1.w = y1.w * (z1.w / (1.f + expf(-z1.w))) * rs * w1.w;
            *reinterpret_cast<short8*>(&As[ar * 72 + ak]) = pack8f(y0, y1);
        }
        GEMM_STAGE_B(wt, 256, k0);
        __syncthreads();
        GEMM_COMPUTE_TILE();
    }
    #pragma unroll
    for (int nt = 0; nt < 4; nt++) {
        int col = ngrp * 64 + nt * 16 + m;
        #pragma unroll
        for (int r = 0; r < 4; r++) {
            int row = row0 + mrow + (lane >> 4) * 4 + r;
            size_t i = (size_t)row * DM + col;
            h[i] = h[i] + acc[nt][r];
        }
    }
}

// ---------------- fc2a + fc2b fused ----------------
__global__ __launch_bounds__(512) void fc2ab_mfma(const float* __restrict__ h,
                                                  const short* __restrict__ wb,
                                                  const float* __restrict__ b1,
                                                  const float* __restrict__ W2,
                                                  const float* __restrict__ b2,
                                                  float* __restrict__ out) {
    __shared__ short As[64 * 72];
    __shared__ short Bt[128 * 72];
    __shared__ float h2s[64][132];
    __shared__ float w2s[768];
    GEMM_PROLOGUE();
    int row0 = blockIdx.x * 64;
    const short* wt = wb + WB_FC2;
    for (int i = tid; i < 768; i += 512) w2s[i] = W2[i];
    for (int kt = 0; kt < 2; kt++) {
        int k0 = kt * 64;
        if (kt) __syncthreads();
        {
            const float* src = h + (size_t)(row0 + ar) * DM + k0 + ak;
            float4 v0 = *(const float4*)src;
            float4 v1 = *(const float4*)(src + 4);
            *reinterpret_cast<short8*>(&As[ar * 72 + ak]) = pack8f(v0, v1);
        }
        GEMM_STAGE_B(wt, 128, k0);
        __syncthreads();
        GEMM_COMPUTE_TILE();
    }
    #pragma unroll
    for (int nt = 0; nt < 4; nt++) {
        int col = ngrp * 64 + nt * 16 + m;
        float bv = b1[col];
        #pragma unroll
        for (int r = 0; r < 4; r++) {
            int rr = mrow + (lane >> 4) * 4 + r;
            float o = acc[nt][r] + bv;
            h2s[rr][col] = (o > 0.f) ? o : 0.1f * o;
        }
    }
    __syncthreads();
    if (tid < 384) {
        int r = tid / 6, cc = tid % 6;
        float acc2 = b2[cc];
        #pragma unroll 16
        for (int k = 0; k < 128; k++) acc2 += h2s[r][k] * w2s[k * 6 + cc];
        out[(size_t)(row0 + r) * 6 + cc] = acc2;
    }
}

extern "C" void kernel_launch(void* const* d_in, const int* in_sizes, int n_in,
                              void* d_out, int out_size, void* d_ws, size_t ws_size,
                              hipStream_t stream) {
    const float* x       = (const float*)d_in[0];
    const float* fc1_W   = (const float*)d_in[1];
    const float* fc1_b   = (const float*)d_in[2];
    const float* ln_w    = (const float*)d_in[3];
    const float* ln_b    = (const float*)d_in[4];
    const float* in_W    = (const float*)d_in[5];
    const float* conv_w  = (const float*)d_in[6];
    const float* conv_b  = (const float*)d_in[7];
    const float* dt_bias = (const float*)d_in[8];
    const float* A_log   = (const float*)d_in[9];
    const float* Dp      = (const float*)d_in[10];
    const float* rms_w   = (const float*)d_in[11];
    const float* out_W   = (const float*)d_in[12];
    const float* fc2_W1  = (const float*)d_in[13];
    const float* fc2_b1  = (const float*)d_in[14];
    const float* fc2_W2  = (const float*)d_in[15];
    const float* fc2_b2  = (const float*)d_in[16];
    float* out = (float*)d_out;

    float* ws = (float*)d_ws;
    float* h     = ws;                          // 2,097,152
    float* zx    = h     + (size_t)NROWS * DM;  // 10,551,296
    float* xc    = zx    + (size_t)NROWS * DIP; // 6,291,456
    float* dtb   = xc    + (size_t)NROWS * CDIM;// 65,536
    float* yb    = dtb   + (size_t)NROWS * NH;  // 4,194,304
    float* Sloc  = yb    + (size_t)NROWS * DI;  // 4,194,304
    float* hstr  = Sloc  + (size_t)BATCH*NH*NCHUNK*HD*DST; // 4,194,304
    float* decay = hstr  + (size_t)BATCH*NH*NCHUNK*HD*DST; // 1,024
    short* wb    = (short*)(decay + 1024);      // 345,088 shorts (16B-aligned)

    prep_weights<<<1348, 256, 0, stream>>>(fc1_W, in_W, out_W, fc2_W1, wb);
    fc1_mfma<<<NROWS / 64, 512, 0, stream>>>(x, wb + WB_FC1, fc1_b, h);

    for (int layer = 0; layer < 2; layer++) {
        inproj_ln_mfma<<<dim3(NROWS / 64, 6), 512, 0, stream>>>(h, ln_w, ln_b, wb, zx, layer);
        conv_kernel<<<NROWS / 4, CDIM, 0, stream>>>(zx, conv_w, conv_b, dt_bias, xc, dtb, layer);
        chunk_state_mfma<<<BATCH*NH*NCHUNK, 256, 0, stream>>>(xc, dtb, A_log, Sloc, decay, layer);
        chunk_scan_kernel<<<BATCH*NH, 256, 0, stream>>>(Sloc, decay, hstr);
        chunk_out_mfma<<<BATCH*NH*NCHUNK, 256, 0, stream>>>(xc, dtb, A_log, Dp, hstr, yb, layer);
        outproj_gate_mfma<<<NROWS / 64, 512, 0, stream>>>(yb, zx, rms_w, wb, h, layer);
    }

    fc2ab_mfma<<<NROWS / 64, 512, 0, stream>>>(h, wb, fc2_b1, fc2_W2, fc2_b2, out);
}

// Round 7
// 274.782 us; speedup vs baseline: 12.2512x; 1.0965x over previous
//
#include <hip/hip_runtime.h>
#include <hip/hip_bf16.h>

// Dims
#define BATCH 16
#define SEQ 1024
#define NROWS (BATCH*SEQ)          // 16384 tokens
#define IN_DIM 768
#define DM 128
#define DIP 644
#define DI 256
#define CDIM 384
#define DST 64
#define NH 4
#define HD 64
#define CHUNK 64
#define NCHUNK (SEQ/CHUNK)         // 16

// bf16 weight area offsets (in shorts)
#define WB_FC1   0          // [128][768]
#define WB_IN    98304      // [2][644][128]
#define WB_OUT   263168     // [2][128][256]
#define WB_FC2   328704     // [128][128]
#define WB_TOTAL 345088

typedef __attribute__((ext_vector_type(8))) short short8;
typedef __attribute__((ext_vector_type(4))) float float4v;

// f32 -> bf16 (RNE) as raw short
__device__ __forceinline__ short f2b(float f) {
    unsigned u = __builtin_bit_cast(unsigned, f);
    u += 0x7fffu + ((u >> 16) & 1u);
    return (short)(u >> 16);
}
__device__ __forceinline__ float s2f(short s) {
    unsigned u = ((unsigned)(unsigned short)s) << 16;
    return __builtin_bit_cast(float, u);
}
__device__ __forceinline__ short8 pack8f(float4 a, float4 b) {
    short8 r;
    r[0] = f2b(a.x); r[1] = f2b(a.y); r[2] = f2b(a.z); r[3] = f2b(a.w);
    r[4] = f2b(b.x); r[5] = f2b(b.y); r[6] = f2b(b.z); r[7] = f2b(b.w);
    return r;
}

// ---------------- weight prep: convert + transpose to bf16 ----------------
__global__ void prep_weights(const float* __restrict__ fc1_W, const float* __restrict__ in_W,
                             const float* __restrict__ out_W, const float* __restrict__ fc2_W1,
                             short* __restrict__ wb) {
    int idx = blockIdx.x * 256 + threadIdx.x;
    if (idx < 98304) {                       // fc1_Wt[n][k] <- fc1_W[k][n]
        int n = idx / 768, k = idx % 768;
        wb[WB_FC1 + idx] = f2b(fc1_W[k * 128 + n]);
        return;
    }
    idx -= 98304;
    if (idx < 2 * 82432) {                   // in_Wt[l][n][k] <- in_W[l][k][n]
        int l = idx / 82432, r = idx % 82432;
        int n = r / 128, k = r % 128;
        wb[WB_IN + idx] = f2b(in_W[(size_t)l * 82432 + k * 644 + n]);
        return;
    }
    idx -= 164864;
    if (idx < 2 * 32768) {                   // out_Wt[l][n][k] <- out_W[l][k][n]
        int l = idx / 32768, r = idx % 32768;
        int n = r / 256, k = r % 256;
        wb[WB_OUT + idx] = f2b(out_W[(size_t)l * 32768 + k * 128 + n]);
        return;
    }
    idx -= 65536;
    if (idx < 16384) {                       // fc2_W1t[n][k] <- fc2_W1[k][n]
        int n = idx / 128, k = idx % 128;
        wb[WB_FC2 + idx] = f2b(fc2_W1[k * 128 + n]);
    }
}

// ============================================================
// MFMA GEMM tile pattern (block 512 = 8 waves, M=64 x N=128)
// ============================================================
#define GEMM_PROLOGUE() \
    int tid = threadIdx.x; \
    int lane = tid & 63; \
    int m = lane & 15; \
    int kq = (lane >> 4) * 8; \
    int w = tid >> 6; \
    int mrow = (w & 3) * 16; \
    int ngrp = w >> 2; \
    int a_off = (mrow + m) * 72 + kq; \
    int b_off = (ngrp * 64 + m) * 72 + kq; \
    int ar = tid >> 3; \
    int ak = (tid & 7) * 8; \
    (void)ar; (void)ak; \
    float4v acc[4]; \
    acc[0] = (float4v)0.f; acc[1] = (float4v)0.f; acc[2] = (float4v)0.f; acc[3] = (float4v)0.f;

#define GEMM_COMPUTE_TILE() \
    { \
        short8 a0 = *reinterpret_cast<const short8*>(&As[a_off]); \
        short8 a1 = *reinterpret_cast<const short8*>(&As[a_off + 32]); \
        _Pragma("unroll") \
        for (int nt = 0; nt < 4; nt++) { \
            short8 b0 = *reinterpret_cast<const short8*>(&Bt[b_off + nt * 16 * 72]); \
            short8 b1 = *reinterpret_cast<const short8*>(&Bt[b_off + nt * 16 * 72 + 32]); \
            acc[nt] = __builtin_amdgcn_mfma_f32_16x16x32_bf16(a0, b0, acc[nt], 0, 0, 0); \
            acc[nt] = __builtin_amdgcn_mfma_f32_16x16x32_bf16(a1, b1, acc[nt], 0, 0, 0); \
        } \
    }

#define GEMM_STAGE_B(wtptr, LDB, k0) \
    _Pragma("unroll") \
    for (int i = 0; i < 2; i++) { \
        int idx = tid + i * 512; \
        int n = idx >> 3, kk = (idx & 7) * 8; \
        *reinterpret_cast<short8*>(&Bt[n * 72 + kk]) = \
            *reinterpret_cast<const short8*>(&wtptr[n * (LDB) + (k0) + kk]); \
    }

// ---------------- fc1 (MFMA): x@W(768,128)+b+PE -> h ----------------
__global__ __launch_bounds__(512) void fc1_mfma(const float* __restrict__ x,
                                                const short* __restrict__ wt,
                                                const float* __restrict__ bias,
                                                float* __restrict__ h) {
    __shared__ short As[64 * 72];
    __shared__ short Bt[128 * 72];
    GEMM_PROLOGUE();
    int row0 = blockIdx.x * 64;
    for (int kt = 0; kt < 12; kt++) {
        int k0 = kt * 64;
        if (kt) __syncthreads();
        {
            const float* src = x + (size_t)(row0 + ar) * IN_DIM + k0 + ak;
            float4 v0 = *(const float4*)src;
            float4 v1 = *(const float4*)(src + 4);
            *reinterpret_cast<short8*>(&As[ar * 72 + ak]) = pack8f(v0, v1);
        }
        GEMM_STAGE_B(wt, 768, k0);
        __syncthreads();
        GEMM_COMPUTE_TILE();
    }
    #pragma unroll
    for (int nt = 0; nt < 4; nt++) {
        int col = ngrp * 64 + nt * 16 + m;
        float bv = bias[col];
        float div = expf(-(float)(col & ~1) * 0.071955784f);
        #pragma unroll
        for (int r = 0; r < 4; r++) {
            int row = row0 + mrow + (lane >> 4) * 4 + r;
            int t = row & (SEQ - 1);
            float arg = (float)t * div;
            float pe = (col & 1) ? cosf(arg) : sinf(arg);
            h[(size_t)row * DM + col] = acc[nt][r] + bv + pe;
        }
    }
}

// ---------------- in_proj + fused LN; splits output into z(f32)/xbc(bf16)/dtraw(f32) ----------------
__global__ __launch_bounds__(512) void inproj_ln_mfma(const float* __restrict__ h,
                                                      const float* __restrict__ lnw,
                                                      const float* __restrict__ lnb,
                                                      const short* __restrict__ wb,
                                                      float* __restrict__ zbuf,
                                                      short* __restrict__ xbc,
                                                      float* __restrict__ dtraw, int layer) {
    __shared__ short As[64 * 72];
    __shared__ short Bt[128 * 72];
    __shared__ float mu_s[64], rs_s[64];
    GEMM_PROLOGUE();
    int row0 = blockIdx.x * 64;
    int ncol0 = blockIdx.y * 128;
    const short* wt = wb + WB_IN + (size_t)layer * 82432;
    {
        int r = tid >> 3, j = tid & 7;
        const float4* hr = (const float4*)(h + (size_t)(row0 + r) * DM + j * 16);
        float s1 = 0.f, s2 = 0.f;
        #pragma unroll
        for (int i = 0; i < 4; i++) {
            float4 v = hr[i];
            s1 += v.x + v.y + v.z + v.w;
            s2 += v.x * v.x + v.y * v.y + v.z * v.z + v.w * v.w;
        }
        #pragma unroll
        for (int o = 1; o < 8; o <<= 1) { s1 += __shfl_xor(s1, o); s2 += __shfl_xor(s2, o); }
        if (j == 0) {
            float mu = s1 * (1.f / 128.f);
            mu_s[r] = mu;
            rs_s[r] = rsqrtf(s2 * (1.f / 128.f) - mu * mu + 1e-5f);
        }
    }
    __syncthreads();
    for (int kt = 0; kt < 2; kt++) {
        int k0 = kt * 64;
        if (kt) __syncthreads();
        {
            int k = k0 + ak;
            const float* src = h + (size_t)(row0 + ar) * DM + k;
            float4 v0 = *(const float4*)src;
            float4 v1 = *(const float4*)(src + 4);
            float4 w0 = *(const float4*)(lnw + layer * DM + k);
            float4 w1 = *(const float4*)(lnw + layer * DM + k + 4);
            float4 b0 = *(const float4*)(lnb + layer * DM + k);
            float4 b1 = *(const float4*)(lnb + layer * DM + k + 4);
            float mu = mu_s[ar], rs = rs_s[ar];
            v0.x = (v0.x - mu) * rs * w0.x + b0.x; v0.y = (v0.y - mu) * rs * w0.y + b0.y;
            v0.z = (v0.z - mu) * rs * w0.z + b0.z; v0.w = (v0.w - mu) * rs * w0.w + b0.w;
            v1.x = (v1.x - mu) * rs * w1.x + b1.x; v1.y = (v1.y - mu) * rs * w1.y + b1.y;
            v1.z = (v1.z - mu) * rs * w1.z + b1.z; v1.w = (v1.w - mu) * rs * w1.w + b1.w;
            *reinterpret_cast<short8*>(&As[ar * 72 + ak]) = pack8f(v0, v1);
        }
        #pragma unroll
        for (int i = 0; i < 2; i++) {
            int idx = tid + i * 512;
            int n = idx >> 3, kk = (idx & 7) * 8;
            int col = ncol0 + n;
            short8 bv = (short8)0;
            if (col < DIP) bv = *reinterpret_cast<const short8*>(&wt[col * 128 + k0 + kk]);
            *reinterpret_cast<short8*>(&Bt[n * 72 + kk]) = bv;
        }
        __syncthreads();
        GEMM_COMPUTE_TILE();
    }
    #pragma unroll
    for (int nt = 0; nt < 4; nt++) {
        int col = ncol0 + ngrp * 64 + nt * 16 + m;
        if (col < DI) {
            #pragma unroll
            for (int r = 0; r < 4; r++) {
                int row = row0 + mrow + (lane >> 4) * 4 + r;
                zbuf[(size_t)row * DI + col] = acc[nt][r];
            }
        } else if (col < DI + CDIM) {
            #pragma unroll
            for (int r = 0; r < 4; r++) {
                int row = row0 + mrow + (lane >> 4) * 4 + r;
                xbc[(size_t)row * CDIM + (col - DI)] = f2b(acc[nt][r]);
            }
        } else if (col < DIP) {
            #pragma unroll
            for (int r = 0; r < 4; r++) {
                int row = row0 + mrow + (lane >> 4) * 4 + r;
                dtraw[(size_t)row * NH + (col - DI - CDIM)] = acc[nt][r];
            }
        }
    }
}

// ---------------- causal conv(4) + SiLU + dt, 4 tokens/block (bf16 in/out) ----------------
__global__ void conv_kernel(const short* __restrict__ xbc, const float* __restrict__ dtraw,
                            const float* __restrict__ convw, const float* __restrict__ convb,
                            const float* __restrict__ dt_bias,
                            short* __restrict__ xcb, float* __restrict__ dtb, int layer) {
    int c = threadIdx.x;            // 384
    int row0 = blockIdx.x * 4;
    int l0 = row0 & (SEQ - 1);
    const float* cw = convw + (size_t)layer * 4 * CDIM;
    float w0 = cw[c], w1 = cw[CDIM + c], w2 = cw[2 * CDIM + c], w3 = cw[3 * CDIM + c];
    float bb = convb[layer * CDIM + c];
    float v[7];
    #pragma unroll
    for (int i = 0; i < 7; i++) {
        int rr = row0 + i - 3;
        v[i] = (l0 + i - 3 >= 0) ? s2f(xbc[(size_t)rr * CDIM + c]) : 0.f;
    }
    #pragma unroll
    for (int j = 0; j < 4; j++) {
        float acc = bb + w0 * v[j] + w1 * v[j + 1] + w2 * v[j + 2] + w3 * v[j + 3];
        float sv = acc / (1.f + expf(-acc));
        xcb[(size_t)(row0 + j) * CDIM + c] = f2b(sv);
    }
    if (c < 16) {
        int j = c >> 2, hh = c & 3;
        int row = row0 + j;
        float raw = dtraw[(size_t)row * NH + hh] + dt_bias[layer * NH + hh];
        float dt = (raw > 20.f) ? raw : log1pf(expf(raw));
        dtb[row * NH + hh] = dt;
    }
}

// ---------------- chunk A (MFMA): S[p][n] -> bf16 ----------------
__global__ __launch_bounds__(256) void chunk_state_mfma(const short* __restrict__ xcb,
                                                        const float* __restrict__ dtb,
                                                        const float* __restrict__ A_log,
                                                        short* __restrict__ Slocb,
                                                        float* __restrict__ decay, int layer) {
    __shared__ short XTw[64 * 72];   // [p][t]
    __shared__ short BT[64 * 72];    // [n][t]
    __shared__ float wst[64];
    int bid = blockIdx.x;
    int c  = bid & (NCHUNK - 1);
    int hh = (bid >> 4) & (NH - 1);
    int b  = bid >> 6;
    int tid = threadIdx.x;
    int row0 = b * SEQ + c * CHUNK;
    float A = -expf(A_log[layer * NH + hh]);

    if (tid < CHUNK) {
        float dtv = dtb[(row0 + tid) * NH + hh];
        float l = dtv * A;
        #pragma unroll
        for (int o = 1; o < 64; o <<= 1) { float v = __shfl_up(l, o); if (tid >= o) l += v; }
        float Ltot = __shfl(l, 63);
        wst[tid] = expf(Ltot - l) * dtv;
        if (tid == 63) decay[bid] = expf(Ltot);
    }
    __syncthreads();
    {
        int p = tid & 63;
        int tb0 = tid >> 6;
        #pragma unroll
        for (int i = 0; i < 2; i++) {
            int t0 = (tb0 + i * 4) * 8;
            short8 xv, bv;
            #pragma unroll
            for (int j = 0; j < 8; j++) {
                int t = t0 + j;
                const short* xr = xcb + (size_t)(row0 + t) * CDIM;
                xv[j] = f2b(s2f(xr[hh * HD + p]) * wst[t]);
                bv[j] = xr[DI + p];
            }
            *reinterpret_cast<short8*>(&XTw[p * 72 + t0]) = xv;
            *reinterpret_cast<short8*>(&BT[p * 72 + t0]) = bv;
        }
    }
    __syncthreads();

    int lane = tid & 63;
    int m = lane & 15;
    int kq = (lane >> 4) * 8;
    int w = tid >> 6;
    int a_off = (w * 16 + m) * 72 + kq;
    float4v acc[4];
    acc[0] = (float4v)0.f; acc[1] = (float4v)0.f; acc[2] = (float4v)0.f; acc[3] = (float4v)0.f;
    short8 a0 = *reinterpret_cast<const short8*>(&XTw[a_off]);
    short8 a1 = *reinterpret_cast<const short8*>(&XTw[a_off + 32]);
    #pragma unroll
    for (int nt = 0; nt < 4; nt++) {
        int bo = (nt * 16 + m) * 72 + kq;
        short8 b0 = *reinterpret_cast<const short8*>(&BT[bo]);
        short8 b1 = *reinterpret_cast<const short8*>(&BT[bo + 32]);
        acc[nt] = __builtin_amdgcn_mfma_f32_16x16x32_bf16(a0, b0, acc[nt], 0, 0, 0);
        acc[nt] = __builtin_amdgcn_mfma_f32_16x16x32_bf16(a1, b1, acc[nt], 0, 0, 0);
    }
    short* Sp = Slocb + (size_t)bid * (HD * DST);
    int tq = (lane >> 4) * 4;
    #pragma unroll
    for (int nt = 0; nt < 4; nt++) {
        #pragma unroll
        for (int r = 0; r < 4; r++) {
            int p = w * 16 + tq + r;
            int n = nt * 16 + m;
            Sp[p * DST + n] = f2b(acc[nt][r]);   // [p][n] bf16
        }
    }
}

// ---------------- chunk B: inter-chunk recurrence (bf16 io, f32 accum) ----------------
__global__ void chunk_scan_kernel(const short* __restrict__ Slocb, const float* __restrict__ decay,
                                  short* __restrict__ hstrb) {
    int bh = blockIdx.x;
    int tid = threadIdx.x;
    float hreg[16];
    #pragma unroll
    for (int k = 0; k < 16; k++) hreg[k] = 0.f;
    for (int c = 0; c < NCHUNK; c++) {
        size_t base = ((size_t)bh * NCHUNK + c) * (HD * DST) + tid * 16;
        float d = decay[bh * NCHUNK + c];
        short8 s0 = *reinterpret_cast<const short8*>(&Slocb[base]);
        short8 s1 = *reinterpret_cast<const short8*>(&Slocb[base + 8]);
        short8 h0, h1;
        #pragma unroll
        for (int k = 0; k < 8; k++) { h0[k] = f2b(hreg[k]); h1[k] = f2b(hreg[8 + k]); }
        *reinterpret_cast<short8*>(&hstrb[base]) = h0;
        *reinterpret_cast<short8*>(&hstrb[base + 8]) = h1;
        #pragma unroll
        for (int k = 0; k < 8; k++) {
            hreg[k]     = d * hreg[k]     + s2f(s0[k]);
            hreg[8 + k] = d * hreg[8 + k] + s2f(s1[k]);
        }
    }
}

// ---------------- chunk C (MFMA): outputs -> y bf16 ----------------
__global__ __launch_bounds__(256) void chunk_out_mfma(const short* __restrict__ xcb,
                                                      const float* __restrict__ dtb,
                                                      const float* __restrict__ A_log,
                                                      const float* __restrict__ Dpw,
                                                      const short* __restrict__ hstrb,
                                                      short* __restrict__ ybb, int layer) {
    __shared__ short Cb[64 * 72];    // [t][n]
    __shared__ short Bb[64 * 72];    // [s][n], later M[t][s]
    __shared__ short XT[64 * 72];    // [p][t]
    __shared__ short HT[64 * 72];    // [p][n]
    __shared__ float Ls[64], dts[64];
    int bid = blockIdx.x;
    int c  = bid & (NCHUNK - 1);
    int hh = (bid >> 4) & (NH - 1);
    int b  = bid >> 6;
    int tid = threadIdx.x;
    int row0 = b * SEQ + c * CHUNK;
    float A = -expf(A_log[layer * NH + hh]);
    float Dph = Dpw[layer * NH + hh];

    if (tid < CHUNK) {
        float dtv = dtb[(row0 + tid) * NH + hh];
        float l = dtv * A;
        #pragma unroll
        for (int o = 1; o < 64; o <<= 1) { float v = __shfl_up(l, o); if (tid >= o) l += v; }
        Ls[tid] = l;
        dts[tid] = dtv;
    }
    {
        int p = tid & 63;
        int tb0 = tid >> 6;
        #pragma unroll
        for (int i = 0; i < 2; i++) {
            int t0 = (tb0 + i * 4) * 8;
            short8 xv;
            #pragma unroll
            for (int j = 0; j < 8; j++)
                xv[j] = xcb[(size_t)(row0 + t0 + j) * CDIM + hh * HD + p];
            *reinterpret_cast<short8*>(&XT[p * 72 + t0]) = xv;
        }
    }
    #pragma unroll
    for (int i = 0; i < 2; i++) {   // Bb, Cb: direct bf16 copies
        int idx = tid + i * 256;
        int t = idx >> 3, cb = (idx & 7) * 8;
        const short* xr = xcb + (size_t)(row0 + t) * CDIM;
        *reinterpret_cast<short8*>(&Bb[t * 72 + cb]) =
            *reinterpret_cast<const short8*>(&xr[DI + cb]);
        *reinterpret_cast<short8*>(&Cb[t * 72 + cb]) =
            *reinterpret_cast<const short8*>(&xr[DI + DST + cb]);
    }
    {
        const short* hs = hstrb + (size_t)bid * (HD * DST);   // [p][n]
        #pragma unroll
        for (int i = 0; i < 2; i++) {
            int idx = tid + i * 256;
            int pp = idx >> 3, nb = (idx & 7) * 8;
            *reinterpret_cast<short8*>(&HT[pp * 72 + nb]) =
                *reinterpret_cast<const short8*>(&hs[pp * 64 + nb]);
        }
    }
    __syncthreads();

    int lane = tid & 63;
    int m = lane & 15;
    int kq = (lane >> 4) * 8;
    int w = tid >> 6;
    int tq = (lane >> 4) * 4;
    int a_off = (w * 16 + m) * 72 + kq;

    short8 ca0 = *reinterpret_cast<const short8*>(&Cb[a_off]);
    short8 ca1 = *reinterpret_cast<const short8*>(&Cb[a_off + 32]);

    float4v g[4], ir[4];
    #pragma unroll
    for (int i = 0; i < 4; i++) { g[i] = (float4v)0.f; ir[i] = (float4v)0.f; }
    #pragma unroll
    for (int st = 0; st < 4; st++) {
        int bo = (st * 16 + m) * 72 + kq;
        short8 b0 = *reinterpret_cast<const short8*>(&Bb[bo]);
        short8 b1 = *reinterpret_cast<const short8*>(&Bb[bo + 32]);
        g[st] = __builtin_amdgcn_mfma_f32_16x16x32_bf16(ca0, b0, g[st], 0, 0, 0);
        g[st] = __builtin_amdgcn_mfma_f32_16x16x32_bf16(ca1, b1, g[st], 0, 0, 0);
        short8 h0 = *reinterpret_cast<const short8*>(&HT[bo]);
        short8 h1 = *reinterpret_cast<const short8*>(&HT[bo + 32]);
        ir[st] = __builtin_amdgcn_mfma_f32_16x16x32_bf16(ca0, h0, ir[st], 0, 0, 0);
        ir[st] = __builtin_amdgcn_mfma_f32_16x16x32_bf16(ca1, h1, ir[st], 0, 0, 0);
    }
    __syncthreads();
    #pragma unroll
    for (int st = 0; st < 4; st++) {
        #pragma unroll
        for (int r = 0; r < 4; r++) {
            int t = w * 16 + tq + r;
            int s = st * 16 + m;
            float mv = 0.f;
            if (s <= t) mv = g[st][r] * expf(Ls[t] - Ls[s]) * dts[s];
            Bb[t * 72 + s] = f2b(mv);
        }
    }
    __syncthreads();
    float4v yi[4];
    #pragma unroll
    for (int i = 0; i < 4; i++) yi[i] = (float4v)0.f;
    short8 ma0 = *reinterpret_cast<const short8*>(&Bb[a_off]);
    short8 ma1 = *reinterpret_cast<const short8*>(&Bb[a_off + 32]);
    #pragma unroll
    for (int pt = 0; pt < 4; pt++) {
        int bo = (pt * 16 + m) * 72 + kq;
        short8 x0 = *reinterpret_cast<const short8*>(&XT[bo]);
        short8 x1 = *reinterpret_cast<const short8*>(&XT[bo + 32]);
        yi[pt] = __builtin_amdgcn_mfma_f32_16x16x32_bf16(ma0, x0, yi[pt], 0, 0, 0);
        yi[pt] = __builtin_amdgcn_mfma_f32_16x16x32_bf16(ma1, x1, yi[pt], 0, 0, 0);
    }
    #pragma unroll
    for (int r = 0; r < 4; r++) {
        int t = w * 16 + tq + r;
        float et = expf(Ls[t]);
        const short* xr = xcb + (size_t)(row0 + t) * CDIM + hh * HD;
        short* yr = ybb + (size_t)(row0 + t) * DI + hh * HD;
        #pragma unroll
        for (int pt = 0; pt < 4; pt++) {
            int p = pt * 16 + m;
            yr[p] = f2b(yi[pt][r] + et * ir[pt][r] + Dph * s2f(xr[p]));
        }
    }
}

// ---------------- out_proj + fused gate(silu)+RMSNorm + residual ----------------
__global__ __launch_bounds__(512) void outproj_gate_mfma(const short* __restrict__ ybb,
                                                         const float* __restrict__ zbuf,
                                                         const float* __restrict__ rmsw,
                                                         const short* __restrict__ wb,
                                                         float* __restrict__ h, int layer) {
    __shared__ short As[64 * 72];
    __shared__ short Bt[128 * 72];
    __shared__ float rs_s[64];
    GEMM_PROLOGUE();
    int row0 = blockIdx.x * 64;
    const short* wt = wb + WB_OUT + (size_t)layer * 32768;
    {   // RMS stats on v = y*silu(z): 8 threads/row, 32 elems each
        int r = tid >> 3, j = tid & 7;
        const short8* yr = (const short8*)(ybb + (size_t)(row0 + r) * DI + j * 32);
        const float4* zr = (const float4*)(zbuf + (size_t)(row0 + r) * DI + j * 32);
        float s2 = 0.f;
        #pragma unroll
        for (int i = 0; i < 4; i++) {
            short8 yv = yr[i];
            #pragma unroll
            for (int q = 0; q < 2; q++) {
                float4 zv = zr[i * 2 + q];
                float v;
                v = s2f(yv[q*4+0]) * (zv.x / (1.f + expf(-zv.x))); s2 += v * v;
                v = s2f(yv[q*4+1]) * (zv.y / (1.f + expf(-zv.y))); s2 += v * v;
                v = s2f(yv[q*4+2]) * (zv.z / (1.f + expf(-zv.z))); s2 += v * v;
                v = s2f(yv[q*4+3]) * (zv.w / (1.f + expf(-zv.w))); s2 += v * v;
            }
        }
        #pragma unroll
        for (int o = 1; o < 8; o <<= 1) s2 += __shfl_xor(s2, o);
        if (j == 0) rs_s[r] = rsqrtf(s2 * (1.f / 256.f) + 1e-5f);
    }
    __syncthreads();
    for (int kt = 0; kt < 4; kt++) {
        int k0 = kt * 64;
        if (kt) __syncthreads();
        {
            int k = k0 + ak;
            short8 yv = *(const short8*)(ybb + (size_t)(row0 + ar) * DI + k);
            const float* zsrc = zbuf + (size_t)(row0 + ar) * DI + k;
            float4 z0 = *(const float4*)zsrc;
            float4 z1 = *(const float4*)(zsrc + 4);
            float4 w0 = *(const float4*)(rmsw + layer * DI + k);
            float4 w1 = *(const float4*)(rmsw + layer * DI + k + 4);
            float rs = rs_s[ar];
            short8 av;
            av[0] = f2b(s2f(yv[0]) * (z0.x / (1.f + expf(-z0.x))) * rs * w0.x);
            av[1] = f2b(s2f(yv[1]) * (z0.y / (1.f + expf(-z0.y))) * rs * w0.y);
            av[2] = f2b(s2f(yv[2]) * (z0.z / (1.f + expf(-z0.z))) * rs * w0.z);
            av[3] = f2b(s2f(yv[3]) * (z0.w / (1.f + expf(-z0.w))) * rs * w0.w);
            av[4] = f2b(s2f(yv[4]) * (z1.x / (1.f + expf(-z1.x))) * rs * w1.x);
            av[5] = f2b(s2f(yv[5]) * (z1.y / (1.f + expf(-z1.y))) * rs * w1.y);
            av[6] = f2b(s2f(yv[6]) * (z1.z / (1.f + expf(-z1.z))) * rs * w1.z);
            av[7] = f2b(s2f(yv[7]) * (z1.w / (1.f + expf(-z1.w))) * rs * w1.w);
            *reinterpret_cast<short8*>(&As[ar * 72 + ak]) = av;
        }
        GEMM_STAGE_B(wt, 256, k0);
        __syncthreads();
        GEMM_COMPUTE_TILE();
    }
    #pragma unroll
    for (int nt = 0; nt < 4; nt++) {
        int col = ngrp * 64 + nt * 16 + m;
        #pragma unroll
        for (int r = 0; r < 4; r++) {
            int row = row0 + mrow + (lane >> 4) * 4 + r;
            size_t i = (size_t)row * DM + col;
            h[i] = h[i] + acc[nt][r];
        }
    }
}

// ---------------- fc2a + fc2b fused ----------------
__global__ __launch_bounds__(512) void fc2ab_mfma(const float* __restrict__ h,
                                                  const short* __restrict__ wb,
                                                  const float* __restrict__ b1,
                                                  const float* __restrict__ W2,
                                                  const float* __restrict__ b2,
                                                  float* __restrict__ out) {
    __shared__ short As[64 * 72];
    __shared__ short Bt[128 * 72];
    __shared__ float h2s[64][132];
    __shared__ float w2s[768];
    GEMM_PROLOGUE();
    int row0 = blockIdx.x * 64;
    const short* wt = wb + WB_FC2;
    for (int i = tid; i < 768; i += 512) w2s[i] = W2[i];
    for (int kt = 0; kt < 2; kt++) {
        int k0 = kt * 64;
        if (kt) __syncthreads();
        {
            const float* src = h + (size_t)(row0 + ar) * DM + k0 + ak;
            float4 v0 = *(const float4*)src;
            float4 v1 = *(const float4*)(src + 4);
            *reinterpret_cast<short8*>(&As[ar * 72 + ak]) = pack8f(v0, v1);
        }
        GEMM_STAGE_B(wt, 128, k0);
        __syncthreads();
        GEMM_COMPUTE_TILE();
    }
    #pragma unroll
    for (int nt = 0; nt < 4; nt++) {
        int col = ngrp * 64 + nt * 16 + m;
        float bv = b1[col];
        #pragma unroll
        for (int r = 0; r < 4; r++) {
            int rr = mrow + (lane >> 4) * 4 + r;
            float o = acc[nt][r] + bv;
            h2s[rr][col] = (o > 0.f) ? o : 0.1f * o;
        }
    }
    __syncthreads();
    if (tid < 384) {
        int r = tid / 6, cc = tid % 6;
        float acc2 = b2[cc];
        #pragma unroll 16
        for (int k = 0; k < 128; k++) acc2 += h2s[r][k] * w2s[k * 6 + cc];
        out[(size_t)(row0 + r) * 6 + cc] = acc2;
    }
}

extern "C" void kernel_launch(void* const* d_in, const int* in_sizes, int n_in,
                              void* d_out, int out_size, void* d_ws, size_t ws_size,
                              hipStream_t stream) {
    const float* x       = (const float*)d_in[0];
    const float* fc1_W   = (const float*)d_in[1];
    const float* fc1_b   = (const float*)d_in[2];
    const float* ln_w    = (const float*)d_in[3];
    const float* ln_b    = (const float*)d_in[4];
    const float* in_W    = (const float*)d_in[5];
    const float* conv_w  = (const float*)d_in[6];
    const float* conv_b  = (const float*)d_in[7];
    const float* dt_bias = (const float*)d_in[8];
    const float* A_log   = (const float*)d_in[9];
    const float* Dp      = (const float*)d_in[10];
    const float* rms_w   = (const float*)d_in[11];
    const float* out_W   = (const float*)d_in[12];
    const float* fc2_W1  = (const float*)d_in[13];
    const float* fc2_b1  = (const float*)d_in[14];
    const float* fc2_W2  = (const float*)d_in[15];
    const float* fc2_b2  = (const float*)d_in[16];
    float* out = (float*)d_out;

    float* ws = (float*)d_ws;
    float* h     = ws;                            // 2,097,152 f
    float* zbuf  = h     + (size_t)NROWS * DM;    // 4,194,304 f
    float* dtraw = zbuf  + (size_t)NROWS * DI;    // 65,536 f
    float* dtb   = dtraw + (size_t)NROWS * NH;    // 65,536 f
    float* decay = dtb   + (size_t)NROWS * NH;    // 1,024 f
    short* sbase = (short*)(decay + 1024);
    short* xbc   = sbase;                          // 6,291,456 sh
    short* xcb   = xbc   + (size_t)NROWS * CDIM;   // 6,291,456 sh
    short* ybb   = xcb   + (size_t)NROWS * CDIM;   // 4,194,304 sh
    short* Slocb = ybb   + (size_t)NROWS * DI;     // 4,194,304 sh
    short* hstrb = Slocb + (size_t)BATCH*NH*NCHUNK*HD*DST; // 4,194,304 sh
    short* wb    = hstrb + (size_t)BATCH*NH*NCHUNK*HD*DST; // 345,088 sh

    prep_weights<<<1348, 256, 0, stream>>>(fc1_W, in_W, out_W, fc2_W1, wb);
    fc1_mfma<<<NROWS / 64, 512, 0, stream>>>(x, wb + WB_FC1, fc1_b, h);

    for (int layer = 0; layer < 2; layer++) {
        inproj_ln_mfma<<<dim3(NROWS / 64, 6), 512, 0, stream>>>(h, ln_w, ln_b, wb,
                                                                zbuf, xbc, dtraw, layer);
        conv_kernel<<<NROWS / 4, CDIM, 0, stream>>>(xbc, dtraw, conv_w, conv_b, dt_bias,
                                                    xcb, dtb, layer);
        chunk_state_mfma<<<BATCH*NH*NCHUNK, 256, 0, stream>>>(xcb, dtb, A_log, Slocb, decay, layer);
        chunk_scan_kernel<<<BATCH*NH, 256, 0, stream>>>(Slocb, decay, hstrb);
        chunk_out_mfma<<<BATCH*NH*NCHUNK, 256, 0, stream>>>(xcb, dtb, A_log, Dp, hstrb, ybb, layer);
        outproj_gate_mfma<<<NROWS / 64, 512, 0, stream>>>(ybb, zbuf, rms_w, wb, h, layer);
    }

    fc2ab_mfma<<<NROWS / 64, 512, 0, stream>>>(h, wb, fc2_b1, fc2_W2, fc2_b2, out);
}